// Round 1
// baseline (976.993 us; speedup 1.0000x reference)
//
#include <hip/hip_runtime.h>

// MHA fused: B=2, S=2048, D=1024, H=16, DK=64.
// Strategy (round 1, correctness-first):
//  - All GEMMs via mfma_f32_16x16x32_bf16, per-wave 16x64 tiles, no LDS staging.
//  - Error control: hi/lo bf16 split (Markidis) on Q/K projections, QK^T and O
//    projection (3 MFMAs); plain bf16 for V and P@V (softmax-attenuated).
//  - Flash attention: 1 wave owns 16 q-rows, loops 32-key blocks, online softmax,
//    P relayout C/D->A-operand through per-wave LDS slice (no barriers needed).

constexpr int BB = 2;
constexpr int SS = 2048;
constexpr int DD = 1024;
constexpr int HH = 16;
constexpr int DKK = 64;

typedef float f32x4 __attribute__((ext_vector_type(4)));
typedef __bf16 bf16x8 __attribute__((ext_vector_type(8)));
typedef short s16x8 __attribute__((ext_vector_type(8)));

#define DEV static __device__ __forceinline__

DEV f32x4 mfma16(s16x8 a, s16x8 b, f32x4 c) {
  return __builtin_amdgcn_mfma_f32_16x16x32_bf16(
      __builtin_bit_cast(bf16x8, a), __builtin_bit_cast(bf16x8, b), c, 0, 0, 0);
}

DEV short bf_hi(float x) {  // truncate to bf16 bits
  return (short)(__float_as_uint(x) >> 16);
}
DEV void split1(float x, short& h, short& l) {  // x ~= hi + lo (both bf16)
  unsigned u = __float_as_uint(x);
  h = (short)(u >> 16);
  float hf = __uint_as_float(u & 0xffff0000u);
  l = (short)(__float_as_uint(x - hf) >> 16);
}
DEV short f2bf_rne(float x) {  // round-to-nearest-even bf16
  unsigned u = __float_as_uint(x);
  return (short)((u + 0x7fffu + ((u >> 16) & 1u)) >> 16);
}
DEV s16x8 load8s(const short* p) { return *(const s16x8*)p; }

// ---------------------------------------------------------------- split weights
__global__ __launch_bounds__(256) void mha_split_w(const float* __restrict__ W,
                                                   short* __restrict__ Wh,
                                                   short* __restrict__ Wl) {
  int i = (blockIdx.x * 256 + threadIdx.x) * 4;  // grid covers D*D exactly
  float4 x = *(const float4*)(W + i);
  float xs[4] = {x.x, x.y, x.z, x.w};
#pragma unroll
  for (int e = 0; e < 4; ++e) {
    short h, l;
    split1(xs[e], h, l);
    Wh[i + e] = h;
    Wl[i + e] = l;
  }
}

// ---------------------------------------------------------------- GEMM C = A @ W^T + b
// EPI 0: A fp32 (split in-reg), W hi/lo, 3-mfma; out -> bf16 hi/lo [B,H,S,DK]
// EPI 1: A fp32 (plain),       W hi,    1-mfma; out -> bf16 [B,H,DK,S] (V transposed)
// EPI 2: A bf16 hi/lo arrays,  W hi/lo, 3-mfma; out -> fp32 [M,D] (= d_out)
template <int EPI>
__global__ __launch_bounds__(256) void mha_gemm_bt(
    const void* __restrict__ Ap, const void* __restrict__ Ap2,
    const short* __restrict__ Wh, const short* __restrict__ Wl,
    const float* __restrict__ bias, void* __restrict__ O1, void* __restrict__ O2) {
  const int lane = threadIdx.x & 63;
  const int wv = threadIdx.x >> 6;
  const int tid4 = blockIdx.x * 4 + wv;  // 4096 wave-tiles
  const int m0 = (tid4 & 255) * 16;      // M = 4096
  const int n0 = (tid4 >> 8) * 64;      // N = 1024, 64 cols per wave
  const int lo16 = lane & 15, quad = lane >> 4;

  f32x4 acc[4];
#pragma unroll
  for (int t = 0; t < 4; ++t) acc[t] = f32x4{0.f, 0.f, 0.f, 0.f};

  const size_t abase = (size_t)(m0 + lo16) * DD + quad * 8;
  const size_t wbase = (size_t)(n0 + lo16) * DD + quad * 8;

  const float* Af = (const float*)Ap;
  const short* Abh = (const short*)Ap;
  const short* Abl = (const short*)Ap2;

  for (int k0 = 0; k0 < DD; k0 += 32) {
    s16x8 ah, al;
    if constexpr (EPI == 2) {
      ah = load8s(Abh + abase + k0);
      al = load8s(Abl + abase + k0);
    } else {
      float4 x0 = *(const float4*)(Af + abase + k0);
      float4 x1 = *(const float4*)(Af + abase + k0 + 4);
      float xs[8] = {x0.x, x0.y, x0.z, x0.w, x1.x, x1.y, x1.z, x1.w};
#pragma unroll
      for (int e = 0; e < 8; ++e) {
        if constexpr (EPI == 0) {
          short h, l;
          split1(xs[e], h, l);
          ah[e] = h;
          al[e] = l;
        } else {
          ah[e] = f2bf_rne(xs[e]);
        }
      }
    }
#pragma unroll
    for (int t = 0; t < 4; ++t) {
      const size_t wo = wbase + (size_t)t * 16 * DD + k0;
      s16x8 wh = load8s(Wh + wo);
      acc[t] = mfma16(ah, wh, acc[t]);
      if constexpr (EPI != 1) {
        s16x8 wl = load8s(Wl + wo);
        acc[t] = mfma16(ah, wl, acc[t]);
        acc[t] = mfma16(al, wh, acc[t]);
      }
    }
  }

#pragma unroll
  for (int t = 0; t < 4; ++t) {
    const int n = n0 + t * 16 + lo16;
    const float bv = bias[n];
#pragma unroll
    for (int r = 0; r < 4; ++r) {
      const int m = m0 + quad * 4 + r;
      const float val = acc[t][r] + bv;
      const int b = m >> 11, s = m & 2047;
      const int h = n >> 6, dk = n & 63;
      if constexpr (EPI == 0) {
        size_t idx = ((size_t)(b * HH + h) * SS + s) * DKK + dk;
        short hh, ll;
        split1(val, hh, ll);
        ((short*)O1)[idx] = hh;
        ((short*)O2)[idx] = ll;
      } else if constexpr (EPI == 1) {
        size_t idx = ((size_t)(b * HH + h) * DKK + dk) * SS + s;
        ((short*)O1)[idx] = f2bf_rne(val);
      } else {
        ((float*)O1)[(size_t)m * DD + n] = val;
      }
    }
  }
}

// ---------------------------------------------------------------- flash attention
__global__ __launch_bounds__(256) void mha_attn(
    const short* __restrict__ Qh, const short* __restrict__ Ql,
    const short* __restrict__ Kh, const short* __restrict__ Kl,
    const short* __restrict__ Vt, const int* __restrict__ mask,
    short* __restrict__ Ah, short* __restrict__ Al) {
  __shared__ short Plds[4][16][32];  // per-wave 16x32 P tile
  const int lane = threadIdx.x & 63;
  const int wv = threadIdx.x >> 6;
  const int wid = blockIdx.x * 4 + wv;  // 4096 waves: b(2) x h(16) x qtile(128)
  const int q0 = (wid & 127) * 16;
  const int h = (wid >> 7) & 15;
  const int b = wid >> 11;
  const int lo16 = lane & 15, quad = lane >> 4;

  const size_t head = (size_t)(b * HH + h) * SS;
  s16x8 qh[2], ql[2];
  {
    size_t qb = (head + q0 + lo16) * DKK + quad * 8;
    qh[0] = load8s(Qh + qb);
    qh[1] = load8s(Qh + qb + 32);
    ql[0] = load8s(Ql + qb);
    ql[1] = load8s(Ql + qb + 32);
  }

  f32x4 Oacc[4];
#pragma unroll
  for (int t = 0; t < 4; ++t) Oacc[t] = f32x4{0.f, 0.f, 0.f, 0.f};
  float m_i[4], l_i[4];
#pragma unroll
  for (int r = 0; r < 4; ++r) {
    m_i[r] = -3.0e38f;
    l_i[r] = 0.f;
  }

  const size_t vbase = ((size_t)(b * HH + h) * DKK + lo16) * SS + quad * 8;
  const int mbase = b * SS + lo16;

  for (int kb = 0; kb < SS / 32; ++kb) {
    f32x4 sc[2];
#pragma unroll
    for (int sub = 0; sub < 2; ++sub) {
      sc[sub] = f32x4{0.f, 0.f, 0.f, 0.f};
      const int key0 = kb * 32 + sub * 16;
      const size_t kba = (head + key0 + lo16) * DKK + quad * 8;
#pragma unroll
      for (int c = 0; c < 2; ++c) {
        s16x8 kh = load8s(Kh + kba + c * 32);
        s16x8 kl = load8s(Kl + kba + c * 32);
        sc[sub] = mfma16(qh[c], kh, sc[sub]);
        sc[sub] = mfma16(qh[c], kl, sc[sub]);
        sc[sub] = mfma16(ql[c], kh, sc[sub]);
      }
      const int mv = mask[mbase + key0];  // key index = key0 + lo16
#pragma unroll
      for (int r = 0; r < 4; ++r)
        sc[sub][r] = mv ? sc[sub][r] * 0.125f : -1e9f;
    }
    // online softmax over this 32-key block (rows = quad*4+r, cols = 16 lanes)
    float alpha[4];
#pragma unroll
    for (int r = 0; r < 4; ++r) {
      float mx = fmaxf(sc[0][r], sc[1][r]);
#pragma unroll
      for (int off = 1; off < 16; off <<= 1) mx = fmaxf(mx, __shfl_xor(mx, off));
      const float mn = fmaxf(m_i[r], mx);
      alpha[r] = __expf(m_i[r] - mn);
      const float p0 = __expf(sc[0][r] - mn);
      const float p1 = __expf(sc[1][r] - mn);
      sc[0][r] = p0;
      sc[1][r] = p1;
      float rs = p0 + p1;
#pragma unroll
      for (int off = 1; off < 16; off <<= 1) rs += __shfl_xor(rs, off);
      l_i[r] = l_i[r] * alpha[r] + rs;
      m_i[r] = mn;
    }
#pragma unroll
    for (int t = 0; t < 4; ++t)
#pragma unroll
      for (int r = 0; r < 4; ++r) Oacc[t][r] *= alpha[r];
    // P: C/D layout -> LDS -> A-operand layout (same-wave, in-order DS ops)
#pragma unroll
    for (int sub = 0; sub < 2; ++sub)
#pragma unroll
      for (int r = 0; r < 4; ++r)
        Plds[wv][quad * 4 + r][sub * 16 + lo16] = bf_hi(sc[sub][r]);
    s16x8 pa = *(const s16x8*)&Plds[wv][lo16][quad * 8];
#pragma unroll
    for (int t = 0; t < 4; ++t) {
      s16x8 vb = load8s(Vt + vbase + (size_t)t * 16 * SS + kb * 32);
      Oacc[t] = mfma16(pa, vb, Oacc[t]);
    }
  }

#pragma unroll
  for (int r = 0; r < 4; ++r) l_i[r] = 1.0f / l_i[r];
#pragma unroll
  for (int t = 0; t < 4; ++t)
#pragma unroll
    for (int r = 0; r < 4; ++r) {
      const float val = Oacc[t][r] * l_i[r];
      const int row = q0 + quad * 4 + r;
      const int col = h * DKK + t * 16 + lo16;
      const size_t idx = ((size_t)b * SS + row) * DD + col;
      short hh, ll;
      split1(val, hh, ll);
      Ah[idx] = hh;
      Al[idx] = ll;
    }
}

// ---------------------------------------------------------------- launch
extern "C" void kernel_launch(void* const* d_in, const int* in_sizes, int n_in,
                              void* d_out, int out_size, void* d_ws, size_t ws_size,
                              hipStream_t stream) {
  const float* q = (const float*)d_in[0];
  const float* k = (const float*)d_in[1];
  const float* v = (const float*)d_in[2];
  const int* mask = (const int*)d_in[3];
  const float* Wq = (const float*)d_in[4];
  const float* bq = (const float*)d_in[5];
  const float* Wk = (const float*)d_in[6];
  const float* bk = (const float*)d_in[7];
  const float* Wv = (const float*)d_in[8];
  const float* bv = (const float*)d_in[9];
  const float* Wo = (const float*)d_in[10];
  const float* bo = (const float*)d_in[11];

  char* ws = (char*)d_ws;
  size_t off = 0;
  auto take = [&](size_t bytes) {
    char* p = ws + off;
    off += (bytes + 255) & ~(size_t)255;
    return p;
  };
  const size_t WE = (size_t)DD * DD;       // 1,048,576
  const size_t TE = (size_t)BB * SS * DD;  // 4,194,304

  short* Wqh = (short*)take(WE * 2);
  short* Wql = (short*)take(WE * 2);
  short* Wkh = (short*)take(WE * 2);
  short* Wkl = (short*)take(WE * 2);
  short* Wvh = (short*)take(WE * 2);
  short* Wvl = (short*)take(WE * 2);
  short* Woh = (short*)take(WE * 2);
  short* Wol = (short*)take(WE * 2);
  short* Qh = (short*)take(TE * 2);
  short* Ql = (short*)take(TE * 2);
  short* Kh = (short*)take(TE * 2);
  short* Kl = (short*)take(TE * 2);
  short* Vt = (short*)take(TE * 2);
  short* Ah = (short*)take(TE * 2);
  short* Al = (short*)take(TE * 2);
  (void)ws_size;  // ~76 MB needed

  mha_split_w<<<1024, 256, 0, stream>>>(Wq, Wqh, Wql);
  mha_split_w<<<1024, 256, 0, stream>>>(Wk, Wkh, Wkl);
  mha_split_w<<<1024, 256, 0, stream>>>(Wv, Wvh, Wvl);
  mha_split_w<<<1024, 256, 0, stream>>>(Wo, Woh, Wol);

  mha_gemm_bt<0><<<1024, 256, 0, stream>>>(q, nullptr, Wqh, Wql, bq, Qh, Ql);
  mha_gemm_bt<0><<<1024, 256, 0, stream>>>(k, nullptr, Wkh, Wkl, bk, Kh, Kl);
  mha_gemm_bt<1><<<1024, 256, 0, stream>>>(v, nullptr, Wvh, nullptr, bv, Vt, nullptr);

  mha_attn<<<1024, 256, 0, stream>>>(Qh, Ql, Kh, Kl, Vt, mask, Ah, Al);

  mha_gemm_bt<2><<<1024, 256, 0, stream>>>(Ah, Al, Woh, Wol, bo, d_out, nullptr);
}

// Round 2
// 682.992 us; speedup vs baseline: 1.4305x; 1.4305x over previous
//
#include <hip/hip_runtime.h>

// MHA fused: B=2, S=2048, D=1024, H=16, DK=64.
// Round 2:
//  - Activations pre-split to bf16 hi/lo (elementwise) so GEMM hot loops are
//    pure bf16 MFMA (no in-loop split VALU).
//  - GEMMs: m97-style 128x64 tile, BK=32, global_load_lds width=16, 2-barrier
//    K-loop, 4 waves/block, grid 512 (2 blocks/CU).
//  - Attention: 64 keys/iter (4 independent 16-key score subtiles), softmax
//    shfl rounds + LDS P round-trip halved; mask staged in LDS; P rounded RNE.

constexpr int BB = 2;
constexpr int SS = 2048;
constexpr int DD = 1024;
constexpr int HH = 16;
constexpr int DKK = 64;

typedef float f32x4 __attribute__((ext_vector_type(4)));
typedef __bf16 bf16x8 __attribute__((ext_vector_type(8)));
typedef short s16x8 __attribute__((ext_vector_type(8)));
typedef short s16x4 __attribute__((ext_vector_type(4)));

#define DEV static __device__ __forceinline__

DEV f32x4 mfma16(s16x8 a, s16x8 b, f32x4 c) {
  return __builtin_amdgcn_mfma_f32_16x16x32_bf16(
      __builtin_bit_cast(bf16x8, a), __builtin_bit_cast(bf16x8, b), c, 0, 0, 0);
}

DEV void split1(float x, short& h, short& l) {  // x ~= hi + lo (both bf16)
  unsigned u = __float_as_uint(x);
  h = (short)(u >> 16);
  float hf = __uint_as_float(u & 0xffff0000u);
  l = (short)(__float_as_uint(x - hf) >> 16);
}
DEV short f2bf_rne(float x) {  // round-to-nearest-even bf16
  unsigned u = __float_as_uint(x);
  return (short)((u + 0x7fffu + ((u >> 16) & 1u)) >> 16);
}
DEV s16x8 load8s(const short* p) { return *(const s16x8*)p; }

DEV void gld_lds16(const short* g, short* l) {
  __builtin_amdgcn_global_load_lds(
      (const __attribute__((address_space(1))) void*)g,
      (__attribute__((address_space(3))) void*)l, 16, 0, 0);
}

// ---------------------------------------------------------------- elementwise
__global__ __launch_bounds__(256) void split_pair(const float* __restrict__ X,
                                                  short* __restrict__ H,
                                                  short* __restrict__ L) {
  int i = (blockIdx.x * 256 + threadIdx.x) * 4;
  float4 x = *(const float4*)(X + i);
  float xs[4] = {x.x, x.y, x.z, x.w};
  s16x4 h4, l4;
#pragma unroll
  for (int e = 0; e < 4; ++e) {
    short h, l;
    split1(xs[e], h, l);
    h4[e] = h;
    l4[e] = l;
  }
  *(s16x4*)(H + i) = h4;
  *(s16x4*)(L + i) = l4;
}

__global__ __launch_bounds__(256) void cast_rne(const float* __restrict__ X,
                                                short* __restrict__ Y) {
  int i = (blockIdx.x * 256 + threadIdx.x) * 4;
  float4 x = *(const float4*)(X + i);
  float xs[4] = {x.x, x.y, x.z, x.w};
  s16x4 y4;
#pragma unroll
  for (int e = 0; e < 4; ++e) y4[e] = f2bf_rne(xs[e]);
  *(s16x4*)(Y + i) = y4;
}

// ---------------------------------------------------------------- GEMM C = A @ W^T + b
// A [4096,1024] bf16 (hi/lo if SPLIT), W [1024,1024] bf16 (hi/lo if SPLIT).
// Tile: 128(M) x 64(N), BK=32. 4 waves/block; wave w owns rows [w*32, w*32+32).
// EPI 0: out hi/lo bf16 -> [B,H,S,DK]   (Q,K)
// EPI 1: out bf16 -> [B,H,DK,S] (V transposed)
// EPI 2: out fp32 -> [4096,1024] (final output)
template <int SPLIT, int EPI>
__global__ __launch_bounds__(256) void gemm_tile(
    const short* __restrict__ Agh, const short* __restrict__ Agl,
    const short* __restrict__ Wgh, const short* __restrict__ Wgl,
    const float* __restrict__ bias, void* __restrict__ O1, void* __restrict__ O2) {
  __shared__ short lds[12288];  // Ah[128*32] Al[128*32] Wh[64*32] Wl[64*32]
  short* sAh = lds;
  short* sAl = lds + 4096;
  short* sWh = lds + 8192;
  short* sWl = lds + 10240;

  const int tid = threadIdx.x;
  const int lane = tid & 63, wv = tid >> 6;
  const int lo16 = lane & 15, quad = lane >> 4;
  const int m0 = (blockIdx.x & 31) * 128;
  const int n0 = (blockIdx.x >> 5) * 64;

  f32x4 acc[2][4];
#pragma unroll
  for (int mt = 0; mt < 2; ++mt)
#pragma unroll
    for (int nt = 0; nt < 4; ++nt) acc[mt][nt] = f32x4{0.f, 0.f, 0.f, 0.f};

  const int rw = tid >> 2, qw = tid & 3;          // W chunk: row rw, 16B chunk qw
  const int ra0 = tid >> 2, ra1 = (tid + 256) >> 2;  // A chunks

  for (int k0 = 0; k0 < DD; k0 += 32) {
    // ---- stage tiles into LDS (wave-lane-contiguous chunks of 16B)
    gld_lds16(Wgh + (size_t)(n0 + rw) * DD + k0 + qw * 8, sWh + tid * 8);
    if constexpr (SPLIT)
      gld_lds16(Wgl + (size_t)(n0 + rw) * DD + k0 + qw * 8, sWl + tid * 8);
    gld_lds16(Agh + (size_t)(m0 + ra0) * DD + k0 + qw * 8, sAh + tid * 8);
    gld_lds16(Agh + (size_t)(m0 + ra1) * DD + k0 + qw * 8, sAh + (tid + 256) * 8);
    if constexpr (SPLIT) {
      gld_lds16(Agl + (size_t)(m0 + ra0) * DD + k0 + qw * 8, sAl + tid * 8);
      gld_lds16(Agl + (size_t)(m0 + ra1) * DD + k0 + qw * 8, sAl + (tid + 256) * 8);
    }
    __syncthreads();

    // ---- fragments from LDS
    s16x8 ah[2], al[2], wh[4], wl[4];
#pragma unroll
    for (int mt = 0; mt < 2; ++mt) {
      const int r = wv * 32 + mt * 16 + lo16;
      ah[mt] = *(const s16x8*)&sAh[r * 32 + quad * 8];
      if constexpr (SPLIT) al[mt] = *(const s16x8*)&sAl[r * 32 + quad * 8];
    }
#pragma unroll
    for (int nt = 0; nt < 4; ++nt) {
      const int r = nt * 16 + lo16;
      wh[nt] = *(const s16x8*)&sWh[r * 32 + quad * 8];
      if constexpr (SPLIT) wl[nt] = *(const s16x8*)&sWl[r * 32 + quad * 8];
    }
#pragma unroll
    for (int mt = 0; mt < 2; ++mt)
#pragma unroll
      for (int nt = 0; nt < 4; ++nt) {
        acc[mt][nt] = mfma16(ah[mt], wh[nt], acc[mt][nt]);
        if constexpr (SPLIT) {
          acc[mt][nt] = mfma16(ah[mt], wl[nt], acc[mt][nt]);
          acc[mt][nt] = mfma16(al[mt], wh[nt], acc[mt][nt]);
        }
      }
    __syncthreads();
  }

  // ---- epilogue
#pragma unroll
  for (int mt = 0; mt < 2; ++mt)
#pragma unroll
    for (int nt = 0; nt < 4; ++nt) {
      const int n = n0 + nt * 16 + lo16;
      const float bv = bias[n];
#pragma unroll
      for (int r = 0; r < 4; ++r) {
        const int m = m0 + wv * 32 + mt * 16 + quad * 4 + r;
        const float val = acc[mt][nt][r] + bv;
        const int b = m >> 11, s = m & 2047;
        const int h = n >> 6, dk = n & 63;
        if constexpr (EPI == 0) {
          size_t idx = ((size_t)(b * HH + h) * SS + s) * DKK + dk;
          short hh, ll;
          split1(val, hh, ll);
          ((short*)O1)[idx] = hh;
          ((short*)O2)[idx] = ll;
        } else if constexpr (EPI == 1) {
          size_t idx = ((size_t)(b * HH + h) * DKK + dk) * SS + s;
          ((short*)O1)[idx] = f2bf_rne(val);
        } else {
          ((float*)O1)[(size_t)m * DD + n] = val;
        }
      }
    }
}

// ---------------------------------------------------------------- flash attention
// 1 wave = 16 q rows; 32 iterations of 64 keys; online softmax.
__global__ __launch_bounds__(256) void mha_attn(
    const short* __restrict__ Qh, const short* __restrict__ Ql,
    const short* __restrict__ Kh, const short* __restrict__ Kl,
    const short* __restrict__ Vt, const int* __restrict__ mask,
    short* __restrict__ Ah, short* __restrict__ Al) {
  __shared__ short Plds[4][16][64];  // per-wave 16x64 P tile
  __shared__ int mlds[SS];
  const int lane = threadIdx.x & 63;
  const int wv = threadIdx.x >> 6;
  const int wid = blockIdx.x * 4 + wv;  // 4096 waves: b(2) x h(16) x qtile(128)
  const int q0 = (wid & 127) * 16;
  const int h = (wid >> 7) & 15;
  const int b = wid >> 11;
  const int lo16 = lane & 15, quad = lane >> 4;

  // stage this batch's mask (block-uniform b)
  for (int i = threadIdx.x; i < SS; i += 256) mlds[i] = mask[b * SS + i];
  __syncthreads();

  const size_t head = (size_t)(b * HH + h) * SS;
  s16x8 qh[2], ql[2];
  {
    size_t qb = (head + q0 + lo16) * DKK + quad * 8;
    qh[0] = load8s(Qh + qb);
    qh[1] = load8s(Qh + qb + 32);
    ql[0] = load8s(Ql + qb);
    ql[1] = load8s(Ql + qb + 32);
  }

  f32x4 Oacc[4];
#pragma unroll
  for (int t = 0; t < 4; ++t) Oacc[t] = f32x4{0.f, 0.f, 0.f, 0.f};
  float m_i[4], l_i[4];
#pragma unroll
  for (int r = 0; r < 4; ++r) {
    m_i[r] = -3.0e38f;
    l_i[r] = 0.f;
  }

  const size_t vbase = ((size_t)(b * HH + h) * DKK + lo16) * SS + quad * 8;

  for (int kb = 0; kb < SS / 64; ++kb) {
    f32x4 sc[4];
#pragma unroll
    for (int sub = 0; sub < 4; ++sub) {
      sc[sub] = f32x4{0.f, 0.f, 0.f, 0.f};
      const int key0 = kb * 64 + sub * 16;
      const size_t kba = (head + key0 + lo16) * DKK + quad * 8;
#pragma unroll
      for (int c = 0; c < 2; ++c) {
        s16x8 kh = load8s(Kh + kba + c * 32);
        s16x8 kl = load8s(Kl + kba + c * 32);
        sc[sub] = mfma16(qh[c], kh, sc[sub]);
        sc[sub] = mfma16(qh[c], kl, sc[sub]);
        sc[sub] = mfma16(ql[c], kh, sc[sub]);
      }
      const int mv = mlds[key0 + lo16];  // key = key0 + lo16
#pragma unroll
      for (int r = 0; r < 4; ++r)
        sc[sub][r] = mv ? sc[sub][r] * 0.125f : -1e9f;
    }
    // online softmax (rows = quad*4+r, cols across 16 lanes x 4 subtiles)
    float alpha[4];
#pragma unroll
    for (int r = 0; r < 4; ++r) {
      float mx = fmaxf(fmaxf(sc[0][r], sc[1][r]), fmaxf(sc[2][r], sc[3][r]));
#pragma unroll
      for (int off = 1; off < 16; off <<= 1) mx = fmaxf(mx, __shfl_xor(mx, off));
      const float mn = fmaxf(m_i[r], mx);
      alpha[r] = __expf(m_i[r] - mn);
      float rs = 0.f;
#pragma unroll
      for (int sub = 0; sub < 4; ++sub) {
        const float p = __expf(sc[sub][r] - mn);
        sc[sub][r] = p;
        rs += p;
      }
#pragma unroll
      for (int off = 1; off < 16; off <<= 1) rs += __shfl_xor(rs, off);
      l_i[r] = l_i[r] * alpha[r] + rs;
      m_i[r] = mn;
    }
#pragma unroll
    for (int t = 0; t < 4; ++t)
#pragma unroll
      for (int r = 0; r < 4; ++r) Oacc[t][r] *= alpha[r];
    // P: C/D layout -> LDS -> A-operand layout (same-wave, in-order DS ops)
#pragma unroll
    for (int sub = 0; sub < 4; ++sub)
#pragma unroll
      for (int r = 0; r < 4; ++r)
        Plds[wv][quad * 4 + r][sub * 16 + lo16] = f2bf_rne(sc[sub][r]);
    s16x8 pa[2];
#pragma unroll
    for (int c = 0; c < 2; ++c)
      pa[c] = *(const s16x8*)&Plds[wv][lo16][c * 32 + quad * 8];
#pragma unroll
    for (int t = 0; t < 4; ++t)
#pragma unroll
      for (int c = 0; c < 2; ++c) {
        s16x8 vb = load8s(Vt + vbase + (size_t)t * 16 * SS + kb * 64 + c * 32);
        Oacc[t] = mfma16(pa[c], vb, Oacc[t]);
      }
  }

#pragma unroll
  for (int r = 0; r < 4; ++r) l_i[r] = 1.0f / l_i[r];
#pragma unroll
  for (int t = 0; t < 4; ++t)
#pragma unroll
    for (int r = 0; r < 4; ++r) {
      const float val = Oacc[t][r] * l_i[r];
      const int row = q0 + quad * 4 + r;
      const int col = h * DKK + t * 16 + lo16;
      const size_t idx = ((size_t)b * SS + row) * DD + col;
      short hh, ll;
      split1(val, hh, ll);
      Ah[idx] = hh;
      Al[idx] = ll;
    }
}

// ---------------------------------------------------------------- launch
extern "C" void kernel_launch(void* const* d_in, const int* in_sizes, int n_in,
                              void* d_out, int out_size, void* d_ws, size_t ws_size,
                              hipStream_t stream) {
  const float* q = (const float*)d_in[0];
  const float* k = (const float*)d_in[1];
  const float* v = (const float*)d_in[2];
  const int* mask = (const int*)d_in[3];
  const float* Wq = (const float*)d_in[4];
  const float* bq = (const float*)d_in[5];
  const float* Wk = (const float*)d_in[6];
  const float* bk = (const float*)d_in[7];
  const float* Wv = (const float*)d_in[8];
  const float* bv = (const float*)d_in[9];
  const float* Wo = (const float*)d_in[10];
  const float* bo = (const float*)d_in[11];

  char* ws = (char*)d_ws;
  size_t off = 0;
  auto take = [&](size_t bytes) {
    char* p = ws + off;
    off += (bytes + 255) & ~(size_t)255;
    return p;
  };
  const size_t WE = (size_t)DD * DD;       // 1,048,576
  const size_t TE = (size_t)BB * SS * DD;  // 4,194,304

  short* Wqh = (short*)take(WE * 2);
  short* Wql = (short*)take(WE * 2);
  short* Wkh = (short*)take(WE * 2);
  short* Wkl = (short*)take(WE * 2);
  short* Wvh = (short*)take(WE * 2);
  short* Woh = (short*)take(WE * 2);
  short* Wol = (short*)take(WE * 2);
  short* actH = (short*)take(TE * 2);
  short* actL = (short*)take(TE * 2);
  short* Qh = (short*)take(TE * 2);
  short* Ql = (short*)take(TE * 2);
  short* Kh = (short*)take(TE * 2);
  short* Kl = (short*)take(TE * 2);
  short* Vt = (short*)take(TE * 2);
  (void)ws_size;  // ~70 MB needed

  // weights
  split_pair<<<1024, 256, 0, stream>>>(Wq, Wqh, Wql);
  split_pair<<<1024, 256, 0, stream>>>(Wk, Wkh, Wkl);
  split_pair<<<1024, 256, 0, stream>>>(Wo, Woh, Wol);
  cast_rne<<<1024, 256, 0, stream>>>(Wv, Wvh);

  // Q projection
  split_pair<<<4096, 256, 0, stream>>>(q, actH, actL);
  gemm_tile<1, 0><<<512, 256, 0, stream>>>(actH, actL, Wqh, Wql, bq, Qh, Ql);
  // K projection
  split_pair<<<4096, 256, 0, stream>>>(k, actH, actL);
  gemm_tile<1, 0><<<512, 256, 0, stream>>>(actH, actL, Wkh, Wkl, bk, Kh, Kl);
  // V projection (plain bf16, transposed output)
  cast_rne<<<4096, 256, 0, stream>>>(v, actH);
  gemm_tile<0, 1><<<512, 256, 0, stream>>>(actH, nullptr, Wvh, nullptr, bv, Vt, nullptr);

  // attention -> actH/actL reused as attention output hi/lo [4096,1024]
  mha_attn<<<1024, 256, 0, stream>>>(Qh, Ql, Kh, Kl, Vt, mask, actH, actL);

  // output projection
  gemm_tile<1, 2><<<512, 256, 0, stream>>>(actH, actL, Woh, Wol, bo, d_out, nullptr);
}

// Round 3
// 409.709 us; speedup vs baseline: 2.3846x; 1.6670x over previous
//
#include <hip/hip_runtime.h>

// MHA fused: B=2, S=2048, D=1024, H=16, DK=64.
// Round 3:
//  - Attention restructured: block = 64 q-rows of one head (4 waves x 16),
//    K/V tiles (64 keys) staged into LDS once per block-iteration and shared
//    by all 4 waves (was: every wave streamed K/V from global -> latency-bound).
//  - All attn LDS tiles padded to row stride 68 shorts (34 banks) -> 2-way
//    (free) bank access on all ds_read_b128 fragment reads.
//  - XCD-aware head swizzle: blocks resident on one XCD share ~4 heads' K/V.
//  - GEMMs unchanged from round 2 (m97-style 128x64 tile, global_load_lds).

constexpr int BB = 2;
constexpr int SS = 2048;
constexpr int DD = 1024;
constexpr int HH = 16;
constexpr int DKK = 64;

typedef float f32x4 __attribute__((ext_vector_type(4)));
typedef __bf16 bf16x8 __attribute__((ext_vector_type(8)));
typedef short s16x8 __attribute__((ext_vector_type(8)));
typedef short s16x4 __attribute__((ext_vector_type(4)));

#define DEV static __device__ __forceinline__

DEV f32x4 mfma16(s16x8 a, s16x8 b, f32x4 c) {
  return __builtin_amdgcn_mfma_f32_16x16x32_bf16(
      __builtin_bit_cast(bf16x8, a), __builtin_bit_cast(bf16x8, b), c, 0, 0, 0);
}

DEV void split1(float x, short& h, short& l) {  // x ~= hi + lo (both bf16)
  unsigned u = __float_as_uint(x);
  h = (short)(u >> 16);
  float hf = __uint_as_float(u & 0xffff0000u);
  l = (short)(__float_as_uint(x - hf) >> 16);
}
DEV short f2bf_rne(float x) {  // round-to-nearest-even bf16
  unsigned u = __float_as_uint(x);
  return (short)((u + 0x7fffu + ((u >> 16) & 1u)) >> 16);
}
DEV s16x8 load8s(const short* p) { return *(const s16x8*)p; }

DEV void gld_lds16(const short* g, short* l) {
  __builtin_amdgcn_global_load_lds(
      (const __attribute__((address_space(1))) void*)g,
      (__attribute__((address_space(3))) void*)l, 16, 0, 0);
}

// ---------------------------------------------------------------- elementwise
__global__ __launch_bounds__(256) void split_pair(const float* __restrict__ X,
                                                  short* __restrict__ H,
                                                  short* __restrict__ L) {
  int i = (blockIdx.x * 256 + threadIdx.x) * 4;
  float4 x = *(const float4*)(X + i);
  float xs[4] = {x.x, x.y, x.z, x.w};
  s16x4 h4, l4;
#pragma unroll
  for (int e = 0; e < 4; ++e) {
    short h, l;
    split1(xs[e], h, l);
    h4[e] = h;
    l4[e] = l;
  }
  *(s16x4*)(H + i) = h4;
  *(s16x4*)(L + i) = l4;
}

__global__ __launch_bounds__(256) void cast_rne(const float* __restrict__ X,
                                                short* __restrict__ Y) {
  int i = (blockIdx.x * 256 + threadIdx.x) * 4;
  float4 x = *(const float4*)(X + i);
  float xs[4] = {x.x, x.y, x.z, x.w};
  s16x4 y4;
#pragma unroll
  for (int e = 0; e < 4; ++e) y4[e] = f2bf_rne(xs[e]);
  *(s16x4*)(Y + i) = y4;
}

// ---------------------------------------------------------------- GEMM C = A @ W^T + b
template <int SPLIT, int EPI>
__global__ __launch_bounds__(256) void gemm_tile(
    const short* __restrict__ Agh, const short* __restrict__ Agl,
    const short* __restrict__ Wgh, const short* __restrict__ Wgl,
    const float* __restrict__ bias, void* __restrict__ O1, void* __restrict__ O2) {
  __shared__ short lds[12288];  // Ah[128*32] Al[128*32] Wh[64*32] Wl[64*32]
  short* sAh = lds;
  short* sAl = lds + 4096;
  short* sWh = lds + 8192;
  short* sWl = lds + 10240;

  const int tid = threadIdx.x;
  const int lane = tid & 63, wv = tid >> 6;
  const int lo16 = lane & 15, quad = lane >> 4;
  const int m0 = (blockIdx.x & 31) * 128;
  const int n0 = (blockIdx.x >> 5) * 64;

  f32x4 acc[2][4];
#pragma unroll
  for (int mt = 0; mt < 2; ++mt)
#pragma unroll
    for (int nt = 0; nt < 4; ++nt) acc[mt][nt] = f32x4{0.f, 0.f, 0.f, 0.f};

  const int rw = tid >> 2, qw = tid & 3;
  const int ra0 = tid >> 2, ra1 = (tid + 256) >> 2;

  for (int k0 = 0; k0 < DD; k0 += 32) {
    gld_lds16(Wgh + (size_t)(n0 + rw) * DD + k0 + qw * 8, sWh + tid * 8);
    if constexpr (SPLIT)
      gld_lds16(Wgl + (size_t)(n0 + rw) * DD + k0 + qw * 8, sWl + tid * 8);
    gld_lds16(Agh + (size_t)(m0 + ra0) * DD + k0 + qw * 8, sAh + tid * 8);
    gld_lds16(Agh + (size_t)(m0 + ra1) * DD + k0 + qw * 8, sAh + (tid + 256) * 8);
    if constexpr (SPLIT) {
      gld_lds16(Agl + (size_t)(m0 + ra0) * DD + k0 + qw * 8, sAl + tid * 8);
      gld_lds16(Agl + (size_t)(m0 + ra1) * DD + k0 + qw * 8, sAl + (tid + 256) * 8);
    }
    __syncthreads();

    s16x8 ah[2], al[2], wh[4], wl[4];
#pragma unroll
    for (int mt = 0; mt < 2; ++mt) {
      const int r = wv * 32 + mt * 16 + lo16;
      ah[mt] = *(const s16x8*)&sAh[r * 32 + quad * 8];
      if constexpr (SPLIT) al[mt] = *(const s16x8*)&sAl[r * 32 + quad * 8];
    }
#pragma unroll
    for (int nt = 0; nt < 4; ++nt) {
      const int r = nt * 16 + lo16;
      wh[nt] = *(const s16x8*)&sWh[r * 32 + quad * 8];
      if constexpr (SPLIT) wl[nt] = *(const s16x8*)&sWl[r * 32 + quad * 8];
    }
#pragma unroll
    for (int mt = 0; mt < 2; ++mt)
#pragma unroll
      for (int nt = 0; nt < 4; ++nt) {
        acc[mt][nt] = mfma16(ah[mt], wh[nt], acc[mt][nt]);
        if constexpr (SPLIT) {
          acc[mt][nt] = mfma16(ah[mt], wl[nt], acc[mt][nt]);
          acc[mt][nt] = mfma16(al[mt], wh[nt], acc[mt][nt]);
        }
      }
    __syncthreads();
  }

#pragma unroll
  for (int mt = 0; mt < 2; ++mt)
#pragma unroll
    for (int nt = 0; nt < 4; ++nt) {
      const int n = n0 + nt * 16 + lo16;
      const float bv = bias[n];
#pragma unroll
      for (int r = 0; r < 4; ++r) {
        const int m = m0 + wv * 32 + mt * 16 + quad * 4 + r;
        const float val = acc[mt][nt][r] + bv;
        const int b = m >> 11, s = m & 2047;
        const int h = n >> 6, dk = n & 63;
        if constexpr (EPI == 0) {
          size_t idx = ((size_t)(b * HH + h) * SS + s) * DKK + dk;
          short hh, ll;
          split1(val, hh, ll);
          ((short*)O1)[idx] = hh;
          ((short*)O2)[idx] = ll;
        } else if constexpr (EPI == 1) {
          size_t idx = ((size_t)(b * HH + h) * DKK + dk) * SS + s;
          ((short*)O1)[idx] = f2bf_rne(val);
        } else {
          ((float*)O1)[(size_t)m * DD + n] = val;
        }
      }
    }
}

// ---------------------------------------------------------------- flash attention
// Block = 64 q-rows of one head (4 waves x 16 rows). K/V staged in LDS per
// 64-key iteration, shared by all 4 waves. Row stride 68 shorts (34 banks)
// -> 2-way (free) bank access on all b128 fragment reads.
constexpr int PAD = 68;

__global__ __launch_bounds__(256, 4) void mha_attn(
    const short* __restrict__ Qh, const short* __restrict__ Ql,
    const short* __restrict__ Kh, const short* __restrict__ Kl,
    const short* __restrict__ Vt, const int* __restrict__ mask,
    short* __restrict__ Ah, short* __restrict__ Al) {
  __shared__ short sKh[64 * PAD];
  __shared__ short sKl[64 * PAD];
  __shared__ short sV[64 * PAD];
  __shared__ short sP[4][16 * PAD];

  const int tid = threadIdx.x;
  const int lane = tid & 63, wv = tid >> 6;
  const int lo16 = lane & 15, quad = lane >> 4;
  const int bid = blockIdx.x;
  // XCD swizzle: blocks with the same (bid & 7) share 4 heads' K/V in L2.
  const int head = (bid & 7) * 4 + ((bid >> 3) & 3);  // = b*16 + h
  const int q0 = (bid >> 5) * 64 + wv * 16;           // this wave's 16 q rows
  const int b = head >> 4;

  const size_t hbase = (size_t)head * SS;

  s16x8 qh[2], ql[2];
  {
    size_t qb = (hbase + q0 + lo16) * DKK + quad * 8;
    qh[0] = load8s(Qh + qb);
    qh[1] = load8s(Qh + qb + 32);
    ql[0] = load8s(Ql + qb);
    ql[1] = load8s(Ql + qb + 32);
  }

  f32x4 Oacc[4];
#pragma unroll
  for (int t = 0; t < 4; ++t) Oacc[t] = f32x4{0.f, 0.f, 0.f, 0.f};
  float m_i[4], l_i[4];
#pragma unroll
  for (int r = 0; r < 4; ++r) {
    m_i[r] = -3.0e38f;
    l_i[r] = 0.f;
  }

  const int srow = tid >> 2;  // staging row 0..63

  for (int kb = 0; kb < SS / 64; ++kb) {
    const int k0g = kb * 64;
    // ---- stage Kh/Kl/V tiles (64 x 64 each) into padded LDS
#pragma unroll
    for (int i = 0; i < 2; ++i) {
      const int sc_ = (tid & 3) * 8 + i * 32;  // col in shorts
      s16x8 xk = load8s(Kh + (hbase + k0g + srow) * DKK + sc_);
      s16x8 xl = load8s(Kl + (hbase + k0g + srow) * DKK + sc_);
      s16x8 xv = load8s(Vt + ((size_t)head * DKK + srow) * SS + k0g + sc_);
      *(s16x8*)&sKh[srow * PAD + sc_] = xk;
      *(s16x8*)&sKl[srow * PAD + sc_] = xl;
      *(s16x8*)&sV[srow * PAD + sc_] = xv;
    }
    __syncthreads();

    // ---- scores: 4 x (16q x 16k) sub-tiles
    f32x4 sc4[4];
#pragma unroll
    for (int sub = 0; sub < 4; ++sub) {
      sc4[sub] = f32x4{0.f, 0.f, 0.f, 0.f};
      const int krow = sub * 16 + lo16;
#pragma unroll
      for (int c = 0; c < 2; ++c) {
        s16x8 kh = *(const s16x8*)&sKh[krow * PAD + c * 32 + quad * 8];
        s16x8 kl = *(const s16x8*)&sKl[krow * PAD + c * 32 + quad * 8];
        sc4[sub] = mfma16(qh[c], kh, sc4[sub]);
        sc4[sub] = mfma16(qh[c], kl, sc4[sub]);
        sc4[sub] = mfma16(ql[c], kh, sc4[sub]);
      }
      const int mv = mask[b * SS + k0g + sub * 16 + lo16];
#pragma unroll
      for (int r = 0; r < 4; ++r)
        sc4[sub][r] = mv ? sc4[sub][r] * 0.125f : -1e9f;
    }

    // ---- online softmax (rows = quad*4+r; cols = 16 lanes x 4 subtiles)
    float alpha[4];
#pragma unroll
    for (int r = 0; r < 4; ++r) {
      float mx = fmaxf(fmaxf(sc4[0][r], sc4[1][r]), fmaxf(sc4[2][r], sc4[3][r]));
#pragma unroll
      for (int off = 1; off < 16; off <<= 1) mx = fmaxf(mx, __shfl_xor(mx, off));
      const float mn = fmaxf(m_i[r], mx);
      alpha[r] = __expf(m_i[r] - mn);
      float rs = 0.f;
#pragma unroll
      for (int sub = 0; sub < 4; ++sub) {
        const float p = __expf(sc4[sub][r] - mn);
        sc4[sub][r] = p;
        rs += p;
      }
#pragma unroll
      for (int off = 1; off < 16; off <<= 1) rs += __shfl_xor(rs, off);
      l_i[r] = l_i[r] * alpha[r] + rs;
      m_i[r] = mn;
    }
#pragma unroll
    for (int t = 0; t < 4; ++t)
#pragma unroll
      for (int r = 0; r < 4; ++r) Oacc[t][r] *= alpha[r];

    // ---- P: C/D layout -> LDS -> A-operand layout (per-wave slice)
#pragma unroll
    for (int sub = 0; sub < 4; ++sub)
#pragma unroll
      for (int r = 0; r < 4; ++r)
        sP[wv][(quad * 4 + r) * PAD + sub * 16 + lo16] = f2bf_rne(sc4[sub][r]);
    s16x8 pa[2];
#pragma unroll
    for (int c = 0; c < 2; ++c)
      pa[c] = *(const s16x8*)&sP[wv][lo16 * PAD + c * 32 + quad * 8];

    // ---- O += P @ V^T-tile
#pragma unroll
    for (int t = 0; t < 4; ++t)
#pragma unroll
      for (int c = 0; c < 2; ++c) {
        s16x8 vb = *(const s16x8*)&sV[(t * 16 + lo16) * PAD + c * 32 + quad * 8];
        Oacc[t] = mfma16(pa[c], vb, Oacc[t]);
      }
    __syncthreads();
  }

  // ---- epilogue: O / l_i -> hi/lo bf16 at [b, row, h*64 + col]
#pragma unroll
  for (int r = 0; r < 4; ++r) l_i[r] = 1.0f / l_i[r];
  const int h = head & 15;
#pragma unroll
  for (int t = 0; t < 4; ++t)
#pragma unroll
    for (int r = 0; r < 4; ++r) {
      const float val = Oacc[t][r] * l_i[r];
      const int row = q0 + quad * 4 + r;
      const int col = h * DKK + t * 16 + lo16;
      const size_t idx = ((size_t)b * SS + row) * DD + col;
      short hh, ll;
      split1(val, hh, ll);
      Ah[idx] = hh;
      Al[idx] = ll;
    }
}

// ---------------------------------------------------------------- launch
extern "C" void kernel_launch(void* const* d_in, const int* in_sizes, int n_in,
                              void* d_out, int out_size, void* d_ws, size_t ws_size,
                              hipStream_t stream) {
  const float* q = (const float*)d_in[0];
  const float* k = (const float*)d_in[1];
  const float* v = (const float*)d_in[2];
  const int* mask = (const int*)d_in[3];
  const float* Wq = (const float*)d_in[4];
  const float* bq = (const float*)d_in[5];
  const float* Wk = (const float*)d_in[6];
  const float* bk = (const float*)d_in[7];
  const float* Wv = (const float*)d_in[8];
  const float* bv = (const float*)d_in[9];
  const float* Wo = (const float*)d_in[10];
  const float* bo = (const float*)d_in[11];

  char* ws = (char*)d_ws;
  size_t off = 0;
  auto take = [&](size_t bytes) {
    char* p = ws + off;
    off += (bytes + 255) & ~(size_t)255;
    return p;
  };
  const size_t WE = (size_t)DD * DD;       // 1,048,576
  const size_t TE = (size_t)BB * SS * DD;  // 4,194,304

  short* Wqh = (short*)take(WE * 2);
  short* Wql = (short*)take(WE * 2);
  short* Wkh = (short*)take(WE * 2);
  short* Wkl = (short*)take(WE * 2);
  short* Wvh = (short*)take(WE * 2);
  short* Woh = (short*)take(WE * 2);
  short* Wol = (short*)take(WE * 2);
  short* actH = (short*)take(TE * 2);
  short* actL = (short*)take(TE * 2);
  short* Qh = (short*)take(TE * 2);
  short* Ql = (short*)take(TE * 2);
  short* Kh = (short*)take(TE * 2);
  short* Kl = (short*)take(TE * 2);
  short* Vt = (short*)take(TE * 2);
  (void)ws_size;  // ~70 MB needed

  // weights
  split_pair<<<1024, 256, 0, stream>>>(Wq, Wqh, Wql);
  split_pair<<<1024, 256, 0, stream>>>(Wk, Wkh, Wkl);
  split_pair<<<1024, 256, 0, stream>>>(Wo, Woh, Wol);
  cast_rne<<<1024, 256, 0, stream>>>(Wv, Wvh);

  // Q projection
  split_pair<<<4096, 256, 0, stream>>>(q, actH, actL);
  gemm_tile<1, 0><<<512, 256, 0, stream>>>(actH, actL, Wqh, Wql, bq, Qh, Ql);
  // K projection
  split_pair<<<4096, 256, 0, stream>>>(k, actH, actL);
  gemm_tile<1, 0><<<512, 256, 0, stream>>>(actH, actL, Wkh, Wkl, bk, Kh, Kl);
  // V projection (plain bf16, transposed output)
  cast_rne<<<4096, 256, 0, stream>>>(v, actH);
  gemm_tile<0, 1><<<512, 256, 0, stream>>>(actH, nullptr, Wvh, nullptr, bv, Vt, nullptr);

  // attention -> actH/actL reused as attention output hi/lo [4096,1024]
  mha_attn<<<1024, 256, 0, stream>>>(Qh, Ql, Kh, Kl, Vt, mask, actH, actL);

  // output projection
  gemm_tile<1, 2><<<512, 256, 0, stream>>>(actH, actL, Woh, Wol, bo, d_out, nullptr);
}

// Round 4
// 342.149 us; speedup vs baseline: 2.8555x; 1.1975x over previous
//
#include <hip/hip_runtime.h>

// MHA fused: B=2, S=2048, D=1024, H=16, DK=64.
// Round 4:
//  - Attention: no-max softmax (scores provably bounded: |s|*0.125 <= 16, exp
//    fits fp32 with huge margin) -> unnormalized P=exp(s), per-lane partial l,
//    ONE cross-lane reduce at epilogue. Deletes all per-iter shfl chains,
//    running max, alpha rescale (the ~50% no-pipe stall of round 3).
//  - 32 q-rows per wave (2 row-tiles share each staged K/V tile) -> LDS reads
//    per score halved. Block = 128 q-rows, grid 512.
//  - Register prefetch of next K/V tile issued right after barrier 1 -> global
//    latency hidden under compute (2 blocks/CU).
//  - GEMMs unchanged from round 3.

constexpr int BB = 2;
constexpr int SS = 2048;
constexpr int DD = 1024;
constexpr int HH = 16;
constexpr int DKK = 64;

typedef float f32x4 __attribute__((ext_vector_type(4)));
typedef __bf16 bf16x8 __attribute__((ext_vector_type(8)));
typedef short s16x8 __attribute__((ext_vector_type(8)));
typedef short s16x4 __attribute__((ext_vector_type(4)));

#define DEV static __device__ __forceinline__

DEV f32x4 mfma16(s16x8 a, s16x8 b, f32x4 c) {
  return __builtin_amdgcn_mfma_f32_16x16x32_bf16(
      __builtin_bit_cast(bf16x8, a), __builtin_bit_cast(bf16x8, b), c, 0, 0, 0);
}

DEV void split1(float x, short& h, short& l) {  // x ~= hi + lo (both bf16)
  unsigned u = __float_as_uint(x);
  h = (short)(u >> 16);
  float hf = __uint_as_float(u & 0xffff0000u);
  l = (short)(__float_as_uint(x - hf) >> 16);
}
DEV short f2bf_rne(float x) {  // round-to-nearest-even bf16
  unsigned u = __float_as_uint(x);
  return (short)((u + 0x7fffu + ((u >> 16) & 1u)) >> 16);
}
DEV s16x8 load8s(const short* p) { return *(const s16x8*)p; }

DEV void gld_lds16(const short* g, short* l) {
  __builtin_amdgcn_global_load_lds(
      (const __attribute__((address_space(1))) void*)g,
      (__attribute__((address_space(3))) void*)l, 16, 0, 0);
}

// ---------------------------------------------------------------- elementwise
__global__ __launch_bounds__(256) void split_pair(const float* __restrict__ X,
                                                  short* __restrict__ H,
                                                  short* __restrict__ L) {
  int i = (blockIdx.x * 256 + threadIdx.x) * 4;
  float4 x = *(const float4*)(X + i);
  float xs[4] = {x.x, x.y, x.z, x.w};
  s16x4 h4, l4;
#pragma unroll
  for (int e = 0; e < 4; ++e) {
    short h, l;
    split1(xs[e], h, l);
    h4[e] = h;
    l4[e] = l;
  }
  *(s16x4*)(H + i) = h4;
  *(s16x4*)(L + i) = l4;
}

__global__ __launch_bounds__(256) void cast_rne(const float* __restrict__ X,
                                                short* __restrict__ Y) {
  int i = (blockIdx.x * 256 + threadIdx.x) * 4;
  float4 x = *(const float4*)(X + i);
  float xs[4] = {x.x, x.y, x.z, x.w};
  s16x4 y4;
#pragma unroll
  for (int e = 0; e < 4; ++e) y4[e] = f2bf_rne(xs[e]);
  *(s16x4*)(Y + i) = y4;
}

// ---------------------------------------------------------------- GEMM C = A @ W^T + b
template <int SPLIT, int EPI>
__global__ __launch_bounds__(256) void gemm_tile(
    const short* __restrict__ Agh, const short* __restrict__ Agl,
    const short* __restrict__ Wgh, const short* __restrict__ Wgl,
    const float* __restrict__ bias, void* __restrict__ O1, void* __restrict__ O2) {
  __shared__ short lds[12288];  // Ah[128*32] Al[128*32] Wh[64*32] Wl[64*32]
  short* sAh = lds;
  short* sAl = lds + 4096;
  short* sWh = lds + 8192;
  short* sWl = lds + 10240;

  const int tid = threadIdx.x;
  const int lane = tid & 63, wv = tid >> 6;
  const int lo16 = lane & 15, quad = lane >> 4;
  const int m0 = (blockIdx.x & 31) * 128;
  const int n0 = (blockIdx.x >> 5) * 64;

  f32x4 acc[2][4];
#pragma unroll
  for (int mt = 0; mt < 2; ++mt)
#pragma unroll
    for (int nt = 0; nt < 4; ++nt) acc[mt][nt] = f32x4{0.f, 0.f, 0.f, 0.f};

  const int rw = tid >> 2, qw = tid & 3;
  const int ra0 = tid >> 2, ra1 = (tid + 256) >> 2;

  for (int k0 = 0; k0 < DD; k0 += 32) {
    gld_lds16(Wgh + (size_t)(n0 + rw) * DD + k0 + qw * 8, sWh + tid * 8);
    if constexpr (SPLIT)
      gld_lds16(Wgl + (size_t)(n0 + rw) * DD + k0 + qw * 8, sWl + tid * 8);
    gld_lds16(Agh + (size_t)(m0 + ra0) * DD + k0 + qw * 8, sAh + tid * 8);
    gld_lds16(Agh + (size_t)(m0 + ra1) * DD + k0 + qw * 8, sAh + (tid + 256) * 8);
    if constexpr (SPLIT) {
      gld_lds16(Agl + (size_t)(m0 + ra0) * DD + k0 + qw * 8, sAl + tid * 8);
      gld_lds16(Agl + (size_t)(m0 + ra1) * DD + k0 + qw * 8, sAl + (tid + 256) * 8);
    }
    __syncthreads();

    s16x8 ah[2], al[2], wh[4], wl[4];
#pragma unroll
    for (int mt = 0; mt < 2; ++mt) {
      const int r = wv * 32 + mt * 16 + lo16;
      ah[mt] = *(const s16x8*)&sAh[r * 32 + quad * 8];
      if constexpr (SPLIT) al[mt] = *(const s16x8*)&sAl[r * 32 + quad * 8];
    }
#pragma unroll
    for (int nt = 0; nt < 4; ++nt) {
      const int r = nt * 16 + lo16;
      wh[nt] = *(const s16x8*)&sWh[r * 32 + quad * 8];
      if constexpr (SPLIT) wl[nt] = *(const s16x8*)&sWl[r * 32 + quad * 8];
    }
#pragma unroll
    for (int mt = 0; mt < 2; ++mt)
#pragma unroll
      for (int nt = 0; nt < 4; ++nt) {
        acc[mt][nt] = mfma16(ah[mt], wh[nt], acc[mt][nt]);
        if constexpr (SPLIT) {
          acc[mt][nt] = mfma16(ah[mt], wl[nt], acc[mt][nt]);
          acc[mt][nt] = mfma16(al[mt], wh[nt], acc[mt][nt]);
        }
      }
    __syncthreads();
  }

#pragma unroll
  for (int mt = 0; mt < 2; ++mt)
#pragma unroll
    for (int nt = 0; nt < 4; ++nt) {
      const int n = n0 + nt * 16 + lo16;
      const float bv = bias[n];
#pragma unroll
      for (int r = 0; r < 4; ++r) {
        const int m = m0 + wv * 32 + mt * 16 + quad * 4 + r;
        const float val = acc[mt][nt][r] + bv;
        const int b = m >> 11, s = m & 2047;
        const int h = n >> 6, dk = n & 63;
        if constexpr (EPI == 0) {
          size_t idx = ((size_t)(b * HH + h) * SS + s) * DKK + dk;
          short hh, ll;
          split1(val, hh, ll);
          ((short*)O1)[idx] = hh;
          ((short*)O2)[idx] = ll;
        } else if constexpr (EPI == 1) {
          size_t idx = ((size_t)(b * HH + h) * DKK + dk) * SS + s;
          ((short*)O1)[idx] = f2bf_rne(val);
        } else {
          ((float*)O1)[(size_t)m * DD + n] = val;
        }
      }
    }
}

// ---------------------------------------------------------------- flash attention
// Block = 128 q-rows of one head (4 waves x 32 rows). K/V staged in LDS per
// 64-key iteration; next tile register-prefetched. No-max softmax:
// P = exp(s/8) (masked -> 0), l accumulated as per-lane partials, single
// cross-lane reduce + normalize at epilogue.
constexpr int PAD = 68;
constexpr int NKB = SS / 64;  // 32

__global__ __launch_bounds__(256, 2) void mha_attn(
    const short* __restrict__ Qh, const short* __restrict__ Ql,
    const short* __restrict__ Kh, const short* __restrict__ Kl,
    const short* __restrict__ Vt, const int* __restrict__ mask,
    short* __restrict__ Ah, short* __restrict__ Al) {
  __shared__ short sKh[64 * PAD];
  __shared__ short sKl[64 * PAD];
  __shared__ short sV[64 * PAD];
  __shared__ short sP[4][32 * PAD];

  const int tid = threadIdx.x;
  const int lane = tid & 63, wv = tid >> 6;
  const int lo16 = lane & 15, quad = lane >> 4;
  const int bid = blockIdx.x;  // 512 blocks
  // XCD swizzle: the 64 blocks per XCD cover 4 heads -> K/V L2-resident.
  const int head = (bid & 7) * 4 + ((bid >> 3) & 3);  // = b*16 + h
  const int qblk = bid >> 5;                          // 0..15
  const int q0 = qblk * 128 + wv * 32;                // this wave's 32 q rows
  const int b = head >> 4;

  const size_t hbase = (size_t)head * SS;

  // Q fragments: 2 row-tiles x 2 k-chunks, hi/lo
  s16x8 qh[2][2], ql[2][2];
#pragma unroll
  for (int rt = 0; rt < 2; ++rt) {
    size_t qb = (hbase + q0 + rt * 16 + lo16) * DKK + quad * 8;
#pragma unroll
    for (int c = 0; c < 2; ++c) {
      qh[rt][c] = load8s(Qh + qb + c * 32);
      ql[rt][c] = load8s(Ql + qb + c * 32);
    }
  }

  f32x4 Oacc[2][4];
#pragma unroll
  for (int rt = 0; rt < 2; ++rt)
#pragma unroll
    for (int t = 0; t < 4; ++t) Oacc[rt][t] = f32x4{0.f, 0.f, 0.f, 0.f};
  float lsum[2][4];
#pragma unroll
  for (int rt = 0; rt < 2; ++rt)
#pragma unroll
    for (int r = 0; r < 4; ++r) lsum[rt][r] = 0.f;

  const int srow = tid >> 2;            // staging row 0..63
  const int scol0 = (tid & 3) * 8;      // staging col (shorts), chunks +0,+32

  // prefetch tile 0 into registers
  s16x8 rKh[2], rKl[2], rV[2];
#pragma unroll
  for (int i = 0; i < 2; ++i) {
    const int sc_ = scol0 + i * 32;
    rKh[i] = load8s(Kh + (hbase + srow) * DKK + sc_);
    rKl[i] = load8s(Kl + (hbase + srow) * DKK + sc_);
    rV[i] = load8s(Vt + ((size_t)head * DKK + srow) * SS + sc_);
  }

  for (int kb = 0; kb < NKB; ++kb) {
    const int k0g = kb * 64;
    // ---- write prefetched tile to LDS
#pragma unroll
    for (int i = 0; i < 2; ++i) {
      const int sc_ = scol0 + i * 32;
      *(s16x8*)&sKh[srow * PAD + sc_] = rKh[i];
      *(s16x8*)&sKl[srow * PAD + sc_] = rKl[i];
      *(s16x8*)&sV[srow * PAD + sc_] = rV[i];
    }
    __syncthreads();

    // ---- issue prefetch for next tile (lands during compute)
    if (kb + 1 < NKB) {
      const int k0n = k0g + 64;
#pragma unroll
      for (int i = 0; i < 2; ++i) {
        const int sc_ = scol0 + i * 32;
        rKh[i] = load8s(Kh + (hbase + k0n + srow) * DKK + sc_);
        rKl[i] = load8s(Kl + (hbase + k0n + srow) * DKK + sc_);
        rV[i] = load8s(Vt + ((size_t)head * DKK + srow) * SS + k0n + sc_);
      }
    }

    // ---- scores: for each 16-key subtile, both row-tiles share K frags
    f32x4 sc4[2][4];
    int mv[4];
#pragma unroll
    for (int sub = 0; sub < 4; ++sub) {
      mv[sub] = mask[b * SS + k0g + sub * 16 + lo16];
      sc4[0][sub] = f32x4{0.f, 0.f, 0.f, 0.f};
      sc4[1][sub] = f32x4{0.f, 0.f, 0.f, 0.f};
      const int krow = sub * 16 + lo16;
#pragma unroll
      for (int c = 0; c < 2; ++c) {
        s16x8 kh = *(const s16x8*)&sKh[krow * PAD + c * 32 + quad * 8];
        s16x8 kl = *(const s16x8*)&sKl[krow * PAD + c * 32 + quad * 8];
#pragma unroll
        for (int rt = 0; rt < 2; ++rt) {
          sc4[rt][sub] = mfma16(qh[rt][c], kh, sc4[rt][sub]);
          sc4[rt][sub] = mfma16(qh[rt][c], kl, sc4[rt][sub]);
          sc4[rt][sub] = mfma16(ql[rt][c], kh, sc4[rt][sub]);
        }
      }
    }

    // ---- P = exp(s/8) (masked -> 0); per-lane l partials; write P to LDS
#pragma unroll
    for (int rt = 0; rt < 2; ++rt)
#pragma unroll
      for (int sub = 0; sub < 4; ++sub)
#pragma unroll
        for (int r = 0; r < 4; ++r) {
          float p = __expf(sc4[rt][sub][r] * 0.125f);
          p = mv[sub] ? p : 0.f;
          lsum[rt][r] += p;
          sP[wv][(rt * 16 + quad * 4 + r) * PAD + sub * 16 + lo16] = f2bf_rne(p);
        }

    // ---- P (A-layout) and V frags; O += P @ V
    s16x8 pa[2][2];
#pragma unroll
    for (int rt = 0; rt < 2; ++rt)
#pragma unroll
      for (int c = 0; c < 2; ++c)
        pa[rt][c] = *(const s16x8*)&sP[wv][(rt * 16 + lo16) * PAD + c * 32 + quad * 8];
#pragma unroll
    for (int t = 0; t < 4; ++t)
#pragma unroll
      for (int c = 0; c < 2; ++c) {
        s16x8 vb = *(const s16x8*)&sV[(t * 16 + lo16) * PAD + c * 32 + quad * 8];
#pragma unroll
        for (int rt = 0; rt < 2; ++rt)
          Oacc[rt][t] = mfma16(pa[rt][c], vb, Oacc[rt][t]);
      }
    __syncthreads();
  }

  // ---- epilogue: reduce l across the 16 lanes of each row, normalize, store
  const int h = head & 15;
#pragma unroll
  for (int rt = 0; rt < 2; ++rt)
#pragma unroll
    for (int r = 0; r < 4; ++r) {
      float s = lsum[rt][r];
#pragma unroll
      for (int off = 1; off < 16; off <<= 1) s += __shfl_xor(s, off);
      const float rinv = 1.0f / s;
#pragma unroll
      for (int t = 0; t < 4; ++t) {
        const float val = Oacc[rt][t][r] * rinv;
        const int row = q0 + rt * 16 + quad * 4 + r;
        const int col = h * DKK + t * 16 + lo16;
        const size_t idx = ((size_t)b * SS + row) * DD + col;
        short hh, ll;
        split1(val, hh, ll);
        Ah[idx] = hh;
        Al[idx] = ll;
      }
    }
}

// ---------------------------------------------------------------- launch
extern "C" void kernel_launch(void* const* d_in, const int* in_sizes, int n_in,
                              void* d_out, int out_size, void* d_ws, size_t ws_size,
                              hipStream_t stream) {
  const float* q = (const float*)d_in[0];
  const float* k = (const float*)d_in[1];
  const float* v = (const float*)d_in[2];
  const int* mask = (const int*)d_in[3];
  const float* Wq = (const float*)d_in[4];
  const float* bq = (const float*)d_in[5];
  const float* Wk = (const float*)d_in[6];
  const float* bk = (const float*)d_in[7];
  const float* Wv = (const float*)d_in[8];
  const float* bv = (const float*)d_in[9];
  const float* Wo = (const float*)d_in[10];
  const float* bo = (const float*)d_in[11];

  char* ws = (char*)d_ws;
  size_t off = 0;
  auto take = [&](size_t bytes) {
    char* p = ws + off;
    off += (bytes + 255) & ~(size_t)255;
    return p;
  };
  const size_t WE = (size_t)DD * DD;       // 1,048,576
  const size_t TE = (size_t)BB * SS * DD;  // 4,194,304

  short* Wqh = (short*)take(WE * 2);
  short* Wql = (short*)take(WE * 2);
  short* Wkh = (short*)take(WE * 2);
  short* Wkl = (short*)take(WE * 2);
  short* Wvh = (short*)take(WE * 2);
  short* Woh = (short*)take(WE * 2);
  short* Wol = (short*)take(WE * 2);
  short* actH = (short*)take(TE * 2);
  short* actL = (short*)take(TE * 2);
  short* Qh = (short*)take(TE * 2);
  short* Ql = (short*)take(TE * 2);
  short* Kh = (short*)take(TE * 2);
  short* Kl = (short*)take(TE * 2);
  short* Vt = (short*)take(TE * 2);
  (void)ws_size;  // ~70 MB needed

  // weights
  split_pair<<<1024, 256, 0, stream>>>(Wq, Wqh, Wql);
  split_pair<<<1024, 256, 0, stream>>>(Wk, Wkh, Wkl);
  split_pair<<<1024, 256, 0, stream>>>(Wo, Woh, Wol);
  cast_rne<<<1024, 256, 0, stream>>>(Wv, Wvh);

  // Q projection
  split_pair<<<4096, 256, 0, stream>>>(q, actH, actL);
  gemm_tile<1, 0><<<512, 256, 0, stream>>>(actH, actL, Wqh, Wql, bq, Qh, Ql);
  // K projection
  split_pair<<<4096, 256, 0, stream>>>(k, actH, actL);
  gemm_tile<1, 0><<<512, 256, 0, stream>>>(actH, actL, Wkh, Wkl, bk, Kh, Kl);
  // V projection (plain bf16, transposed output)
  cast_rne<<<4096, 256, 0, stream>>>(v, actH);
  gemm_tile<0, 1><<<512, 256, 0, stream>>>(actH, nullptr, Wvh, nullptr, bv, Vt, nullptr);

  // attention -> actH/actL reused as attention output hi/lo [4096,1024]
  mha_attn<<<512, 256, 0, stream>>>(Qh, Ql, Kh, Kl, Vt, mask, actH, actL);

  // output projection
  gemm_tile<1, 2><<<512, 256, 0, stream>>>(actH, actL, Woh, Wol, bo, d_out, nullptr);
}

// Round 5
// 334.357 us; speedup vs baseline: 2.9220x; 1.0233x over previous
//
#include <hip/hip_runtime.h>

// MHA fused: B=2, S=2048, D=1024, H=16, DK=64.
// Round 5:
//  - GEMMs: LDS double-buffer. Prefetch of tile k+1 (global_load_lds) is issued
//    right AFTER the barrier, compute reads tile k from the other buffer ->
//    the vmcnt(0) drain at the next barrier waits on loads that had a full
//    MFMA phase in flight. One barrier per k-step (was: stage -> barrier ->
//    compute -> barrier with zero overlap = m93-class 495 TF stall).
//  - Attention unchanged from round 4 (98 us, 69% combined pipe busy).

constexpr int BB = 2;
constexpr int SS = 2048;
constexpr int DD = 1024;
constexpr int HH = 16;
constexpr int DKK = 64;

typedef float f32x4 __attribute__((ext_vector_type(4)));
typedef __bf16 bf16x8 __attribute__((ext_vector_type(8)));
typedef short s16x8 __attribute__((ext_vector_type(8)));
typedef short s16x4 __attribute__((ext_vector_type(4)));

#define DEV static __device__ __forceinline__

DEV f32x4 mfma16(s16x8 a, s16x8 b, f32x4 c) {
  return __builtin_amdgcn_mfma_f32_16x16x32_bf16(
      __builtin_bit_cast(bf16x8, a), __builtin_bit_cast(bf16x8, b), c, 0, 0, 0);
}

DEV void split1(float x, short& h, short& l) {  // x ~= hi + lo (both bf16)
  unsigned u = __float_as_uint(x);
  h = (short)(u >> 16);
  float hf = __uint_as_float(u & 0xffff0000u);
  l = (short)(__float_as_uint(x - hf) >> 16);
}
DEV short f2bf_rne(float x) {  // round-to-nearest-even bf16
  unsigned u = __float_as_uint(x);
  return (short)((u + 0x7fffu + ((u >> 16) & 1u)) >> 16);
}
DEV s16x8 load8s(const short* p) { return *(const s16x8*)p; }

DEV void gld_lds16(const short* g, short* l) {
  __builtin_amdgcn_global_load_lds(
      (const __attribute__((address_space(1))) void*)g,
      (__attribute__((address_space(3))) void*)l, 16, 0, 0);
}

// ---------------------------------------------------------------- elementwise
__global__ __launch_bounds__(256) void split_pair(const float* __restrict__ X,
                                                  short* __restrict__ H,
                                                  short* __restrict__ L) {
  int i = (blockIdx.x * 256 + threadIdx.x) * 4;
  float4 x = *(const float4*)(X + i);
  float xs[4] = {x.x, x.y, x.z, x.w};
  s16x4 h4, l4;
#pragma unroll
  for (int e = 0; e < 4; ++e) {
    short h, l;
    split1(xs[e], h, l);
    h4[e] = h;
    l4[e] = l;
  }
  *(s16x4*)(H + i) = h4;
  *(s16x4*)(L + i) = l4;
}

__global__ __launch_bounds__(256) void cast_rne(const float* __restrict__ X,
                                                short* __restrict__ Y) {
  int i = (blockIdx.x * 256 + threadIdx.x) * 4;
  float4 x = *(const float4*)(X + i);
  float xs[4] = {x.x, x.y, x.z, x.w};
  s16x4 y4;
#pragma unroll
  for (int e = 0; e < 4; ++e) y4[e] = f2bf_rne(xs[e]);
  *(s16x4*)(Y + i) = y4;
}

// ---------------------------------------------------------------- GEMM C = A @ W^T + b
// Tile 128(M) x 64(N), BK=32, LDS double-buffered, one barrier per k-step.
template <int SPLIT, int EPI>
__global__ __launch_bounds__(256) void gemm_tile(
    const short* __restrict__ Agh, const short* __restrict__ Agl,
    const short* __restrict__ Wgh, const short* __restrict__ Wgl,
    const float* __restrict__ bias, void* __restrict__ O1, void* __restrict__ O2) {
  __shared__ short lds[2][12288];  // per buf: Ah[4096] Al[4096] Wh[2048] Wl[2048]

  const int tid = threadIdx.x;
  const int lane = tid & 63, wv = tid >> 6;
  const int lo16 = lane & 15, quad = lane >> 4;
  const int m0 = (blockIdx.x & 31) * 128;
  const int n0 = (blockIdx.x >> 5) * 64;

  f32x4 acc[2][4];
#pragma unroll
  for (int mt = 0; mt < 2; ++mt)
#pragma unroll
    for (int nt = 0; nt < 4; ++nt) acc[mt][nt] = f32x4{0.f, 0.f, 0.f, 0.f};

  const int rw = tid >> 2, qw = tid & 3;
  const int ra0 = tid >> 2, ra1 = (tid + 256) >> 2;

  auto stage = [&](int k0, int buf) {
    short* sAh = lds[buf];
    short* sAl = lds[buf] + 4096;
    short* sWh = lds[buf] + 8192;
    short* sWl = lds[buf] + 10240;
    gld_lds16(Wgh + (size_t)(n0 + rw) * DD + k0 + qw * 8, sWh + tid * 8);
    if constexpr (SPLIT)
      gld_lds16(Wgl + (size_t)(n0 + rw) * DD + k0 + qw * 8, sWl + tid * 8);
    gld_lds16(Agh + (size_t)(m0 + ra0) * DD + k0 + qw * 8, sAh + tid * 8);
    gld_lds16(Agh + (size_t)(m0 + ra1) * DD + k0 + qw * 8, sAh + (tid + 256) * 8);
    if constexpr (SPLIT) {
      gld_lds16(Agl + (size_t)(m0 + ra0) * DD + k0 + qw * 8, sAl + tid * 8);
      gld_lds16(Agl + (size_t)(m0 + ra1) * DD + k0 + qw * 8, sAl + (tid + 256) * 8);
    }
  };

  stage(0, 0);  // prologue: tile 0 -> buf 0

  for (int kk = 0; kk < DD / 32; ++kk) {
    __syncthreads();  // waits tile-kk loads (in flight for a full phase)
    if (kk + 1 < DD / 32) stage((kk + 1) * 32, (kk + 1) & 1);

    const short* sAh = lds[kk & 1];
    const short* sAl = lds[kk & 1] + 4096;
    const short* sWh = lds[kk & 1] + 8192;
    const short* sWl = lds[kk & 1] + 10240;

    s16x8 ah[2], al[2], wh[4], wl[4];
#pragma unroll
    for (int mt = 0; mt < 2; ++mt) {
      const int r = wv * 32 + mt * 16 + lo16;
      ah[mt] = *(const s16x8*)&sAh[r * 32 + quad * 8];
      if constexpr (SPLIT) al[mt] = *(const s16x8*)&sAl[r * 32 + quad * 8];
    }
#pragma unroll
    for (int nt = 0; nt < 4; ++nt) {
      const int r = nt * 16 + lo16;
      wh[nt] = *(const s16x8*)&sWh[r * 32 + quad * 8];
      if constexpr (SPLIT) wl[nt] = *(const s16x8*)&sWl[r * 32 + quad * 8];
    }
#pragma unroll
    for (int mt = 0; mt < 2; ++mt)
#pragma unroll
      for (int nt = 0; nt < 4; ++nt) {
        acc[mt][nt] = mfma16(ah[mt], wh[nt], acc[mt][nt]);
        if constexpr (SPLIT) {
          acc[mt][nt] = mfma16(ah[mt], wl[nt], acc[mt][nt]);
          acc[mt][nt] = mfma16(al[mt], wh[nt], acc[mt][nt]);
        }
      }
  }

#pragma unroll
  for (int mt = 0; mt < 2; ++mt)
#pragma unroll
    for (int nt = 0; nt < 4; ++nt) {
      const int n = n0 + nt * 16 + lo16;
      const float bv = bias[n];
#pragma unroll
      for (int r = 0; r < 4; ++r) {
        const int m = m0 + wv * 32 + mt * 16 + quad * 4 + r;
        const float val = acc[mt][nt][r] + bv;
        const int b = m >> 11, s = m & 2047;
        const int h = n >> 6, dk = n & 63;
        if constexpr (EPI == 0) {
          size_t idx = ((size_t)(b * HH + h) * SS + s) * DKK + dk;
          short hh, ll;
          split1(val, hh, ll);
          ((short*)O1)[idx] = hh;
          ((short*)O2)[idx] = ll;
        } else if constexpr (EPI == 1) {
          size_t idx = ((size_t)(b * HH + h) * DKK + dk) * SS + s;
          ((short*)O1)[idx] = f2bf_rne(val);
        } else {
          ((float*)O1)[(size_t)m * DD + n] = val;
        }
      }
    }
}

// ---------------------------------------------------------------- flash attention
// Block = 128 q-rows of one head (4 waves x 32 rows). K/V staged in LDS per
// 64-key iteration; next tile register-prefetched. No-max softmax:
// P = exp(s/8) (masked -> 0), per-lane partial l, one reduce at epilogue.
constexpr int PAD = 68;
constexpr int NKB = SS / 64;  // 32

__global__ __launch_bounds__(256, 2) void mha_attn(
    const short* __restrict__ Qh, const short* __restrict__ Ql,
    const short* __restrict__ Kh, const short* __restrict__ Kl,
    const short* __restrict__ Vt, const int* __restrict__ mask,
    short* __restrict__ Ah, short* __restrict__ Al) {
  __shared__ short sKh[64 * PAD];
  __shared__ short sKl[64 * PAD];
  __shared__ short sV[64 * PAD];
  __shared__ short sP[4][32 * PAD];

  const int tid = threadIdx.x;
  const int lane = tid & 63, wv = tid >> 6;
  const int lo16 = lane & 15, quad = lane >> 4;
  const int bid = blockIdx.x;  // 512 blocks
  const int head = (bid & 7) * 4 + ((bid >> 3) & 3);  // = b*16 + h
  const int qblk = bid >> 5;                          // 0..15
  const int q0 = qblk * 128 + wv * 32;                // this wave's 32 q rows
  const int b = head >> 4;

  const size_t hbase = (size_t)head * SS;

  s16x8 qh[2][2], ql[2][2];
#pragma unroll
  for (int rt = 0; rt < 2; ++rt) {
    size_t qb = (hbase + q0 + rt * 16 + lo16) * DKK + quad * 8;
#pragma unroll
    for (int c = 0; c < 2; ++c) {
      qh[rt][c] = load8s(Qh + qb + c * 32);
      ql[rt][c] = load8s(Ql + qb + c * 32);
    }
  }

  f32x4 Oacc[2][4];
#pragma unroll
  for (int rt = 0; rt < 2; ++rt)
#pragma unroll
    for (int t = 0; t < 4; ++t) Oacc[rt][t] = f32x4{0.f, 0.f, 0.f, 0.f};
  float lsum[2][4];
#pragma unroll
  for (int rt = 0; rt < 2; ++rt)
#pragma unroll
    for (int r = 0; r < 4; ++r) lsum[rt][r] = 0.f;

  const int srow = tid >> 2;
  const int scol0 = (tid & 3) * 8;

  s16x8 rKh[2], rKl[2], rV[2];
#pragma unroll
  for (int i = 0; i < 2; ++i) {
    const int sc_ = scol0 + i * 32;
    rKh[i] = load8s(Kh + (hbase + srow) * DKK + sc_);
    rKl[i] = load8s(Kl + (hbase + srow) * DKK + sc_);
    rV[i] = load8s(Vt + ((size_t)head * DKK + srow) * SS + sc_);
  }

  for (int kb = 0; kb < NKB; ++kb) {
    const int k0g = kb * 64;
#pragma unroll
    for (int i = 0; i < 2; ++i) {
      const int sc_ = scol0 + i * 32;
      *(s16x8*)&sKh[srow * PAD + sc_] = rKh[i];
      *(s16x8*)&sKl[srow * PAD + sc_] = rKl[i];
      *(s16x8*)&sV[srow * PAD + sc_] = rV[i];
    }
    __syncthreads();

    if (kb + 1 < NKB) {
      const int k0n = k0g + 64;
#pragma unroll
      for (int i = 0; i < 2; ++i) {
        const int sc_ = scol0 + i * 32;
        rKh[i] = load8s(Kh + (hbase + k0n + srow) * DKK + sc_);
        rKl[i] = load8s(Kl + (hbase + k0n + srow) * DKK + sc_);
        rV[i] = load8s(Vt + ((size_t)head * DKK + srow) * SS + k0n + sc_);
      }
    }

    f32x4 sc4[2][4];
    int mv[4];
#pragma unroll
    for (int sub = 0; sub < 4; ++sub) {
      mv[sub] = mask[b * SS + k0g + sub * 16 + lo16];
      sc4[0][sub] = f32x4{0.f, 0.f, 0.f, 0.f};
      sc4[1][sub] = f32x4{0.f, 0.f, 0.f, 0.f};
      const int krow = sub * 16 + lo16;
#pragma unroll
      for (int c = 0; c < 2; ++c) {
        s16x8 kh = *(const s16x8*)&sKh[krow * PAD + c * 32 + quad * 8];
        s16x8 kl = *(const s16x8*)&sKl[krow * PAD + c * 32 + quad * 8];
#pragma unroll
        for (int rt = 0; rt < 2; ++rt) {
          sc4[rt][sub] = mfma16(qh[rt][c], kh, sc4[rt][sub]);
          sc4[rt][sub] = mfma16(qh[rt][c], kl, sc4[rt][sub]);
          sc4[rt][sub] = mfma16(ql[rt][c], kh, sc4[rt][sub]);
        }
      }
    }

#pragma unroll
    for (int rt = 0; rt < 2; ++rt)
#pragma unroll
      for (int sub = 0; sub < 4; ++sub)
#pragma unroll
        for (int r = 0; r < 4; ++r) {
          float p = __expf(sc4[rt][sub][r] * 0.125f);
          p = mv[sub] ? p : 0.f;
          lsum[rt][r] += p;
          sP[wv][(rt * 16 + quad * 4 + r) * PAD + sub * 16 + lo16] = f2bf_rne(p);
        }

    s16x8 pa[2][2];
#pragma unroll
    for (int rt = 0; rt < 2; ++rt)
#pragma unroll
      for (int c = 0; c < 2; ++c)
        pa[rt][c] = *(const s16x8*)&sP[wv][(rt * 16 + lo16) * PAD + c * 32 + quad * 8];
#pragma unroll
    for (int t = 0; t < 4; ++t)
#pragma unroll
      for (int c = 0; c < 2; ++c) {
        s16x8 vb = *(const s16x8*)&sV[(t * 16 + lo16) * PAD + c * 32 + quad * 8];
#pragma unroll
        for (int rt = 0; rt < 2; ++rt)
          Oacc[rt][t] = mfma16(pa[rt][c], vb, Oacc[rt][t]);
      }
    __syncthreads();
  }

  const int h = head & 15;
#pragma unroll
  for (int rt = 0; rt < 2; ++rt)
#pragma unroll
    for (int r = 0; r < 4; ++r) {
      float s = lsum[rt][r];
#pragma unroll
      for (int off = 1; off < 16; off <<= 1) s += __shfl_xor(s, off);
      const float rinv = 1.0f / s;
#pragma unroll
      for (int t = 0; t < 4; ++t) {
        const float val = Oacc[rt][t][r] * rinv;
        const int row = q0 + rt * 16 + quad * 4 + r;
        const int col = h * DKK + t * 16 + lo16;
        const size_t idx = ((size_t)b * SS + row) * DD + col;
        short hh, ll;
        split1(val, hh, ll);
        Ah[idx] = hh;
        Al[idx] = ll;
      }
    }
}

// ---------------------------------------------------------------- launch
extern "C" void kernel_launch(void* const* d_in, const int* in_sizes, int n_in,
                              void* d_out, int out_size, void* d_ws, size_t ws_size,
                              hipStream_t stream) {
  const float* q = (const float*)d_in[0];
  const float* k = (const float*)d_in[1];
  const float* v = (const float*)d_in[2];
  const int* mask = (const int*)d_in[3];
  const float* Wq = (const float*)d_in[4];
  const float* bq = (const float*)d_in[5];
  const float* Wk = (const float*)d_in[6];
  const float* bk = (const float*)d_in[7];
  const float* Wv = (const float*)d_in[8];
  const float* bv = (const float*)d_in[9];
  const float* Wo = (const float*)d_in[10];
  const float* bo = (const float*)d_in[11];

  char* ws = (char*)d_ws;
  size_t off = 0;
  auto take = [&](size_t bytes) {
    char* p = ws + off;
    off += (bytes + 255) & ~(size_t)255;
    return p;
  };
  const size_t WE = (size_t)DD * DD;       // 1,048,576
  const size_t TE = (size_t)BB * SS * DD;  // 4,194,304

  short* Wqh = (short*)take(WE * 2);
  short* Wql = (short*)take(WE * 2);
  short* Wkh = (short*)take(WE * 2);
  short* Wkl = (short*)take(WE * 2);
  short* Wvh = (short*)take(WE * 2);
  short* Woh = (short*)take(WE * 2);
  short* Wol = (short*)take(WE * 2);
  short* actH = (short*)take(TE * 2);
  short* actL = (short*)take(TE * 2);
  short* Qh = (short*)take(TE * 2);
  short* Ql = (short*)take(TE * 2);
  short* Kh = (short*)take(TE * 2);
  short* Kl = (short*)take(TE * 2);
  short* Vt = (short*)take(TE * 2);
  (void)ws_size;  // ~70 MB needed

  // weights
  split_pair<<<1024, 256, 0, stream>>>(Wq, Wqh, Wql);
  split_pair<<<1024, 256, 0, stream>>>(Wk, Wkh, Wkl);
  split_pair<<<1024, 256, 0, stream>>>(Wo, Woh, Wol);
  cast_rne<<<1024, 256, 0, stream>>>(Wv, Wvh);

  // Q projection
  split_pair<<<4096, 256, 0, stream>>>(q, actH, actL);
  gemm_tile<1, 0><<<512, 256, 0, stream>>>(actH, actL, Wqh, Wql, bq, Qh, Ql);
  // K projection
  split_pair<<<4096, 256, 0, stream>>>(k, actH, actL);
  gemm_tile<1, 0><<<512, 256, 0, stream>>>(actH, actL, Wkh, Wkl, bk, Kh, Kl);
  // V projection (plain bf16, transposed output)
  cast_rne<<<4096, 256, 0, stream>>>(v, actH);
  gemm_tile<0, 1><<<512, 256, 0, stream>>>(actH, nullptr, Wvh, nullptr, bv, Vt, nullptr);

  // attention -> actH/actL reused as attention output hi/lo [4096,1024]
  mha_attn<<<512, 256, 0, stream>>>(Qh, Ql, Kh, Kl, Vt, mask, actH, actL);

  // output projection
  gemm_tile<1, 2><<<512, 256, 0, stream>>>(actH, actL, Woh, Wol, bo, d_out, nullptr);
}

// Round 6
// 332.216 us; speedup vs baseline: 2.9408x; 1.0064x over previous
//
#include <hip/hip_runtime.h>

// MHA fused: B=2, S=2048, D=1024, H=16, DK=64.
// Round 6:
//  - Q-proj + K-proj merged into ONE 1024-block dispatch (3 blocks/CU vs the
//    2/CU grid-starved separate 512-block launches; round-5 showed dbuf is
//    neutral -> occupancy, not pipelining, limits this structure).
//  - Q-lo plane dropped: Q is plain RNE bf16 (K stays hi/lo). QK^T = 2 MFMA
//    terms (was 3). Exponent error ~1.1e-3 RMS, margin holds (revert if
//    absmax > 4e-3). Frees 8 MB -> everything fits 70 MB via aliasing.
//  - Buffers aliased: vH<-qH, Vt<-qL, attn-out<-kH/kL.

constexpr int BB = 2;
constexpr int SS = 2048;
constexpr int DD = 1024;
constexpr int HH = 16;
constexpr int DKK = 64;

typedef float f32x4 __attribute__((ext_vector_type(4)));
typedef __bf16 bf16x8 __attribute__((ext_vector_type(8)));
typedef short s16x8 __attribute__((ext_vector_type(8)));
typedef short s16x4 __attribute__((ext_vector_type(4)));

#define DEV static __device__ __forceinline__

DEV f32x4 mfma16(s16x8 a, s16x8 b, f32x4 c) {
  return __builtin_amdgcn_mfma_f32_16x16x32_bf16(
      __builtin_bit_cast(bf16x8, a), __builtin_bit_cast(bf16x8, b), c, 0, 0, 0);
}

DEV void split1(float x, short& h, short& l) {  // x ~= hi + lo (both bf16)
  unsigned u = __float_as_uint(x);
  h = (short)(u >> 16);
  float hf = __uint_as_float(u & 0xffff0000u);
  l = (short)(__float_as_uint(x - hf) >> 16);
}
DEV short f2bf_rne(float x) {  // round-to-nearest-even bf16
  unsigned u = __float_as_uint(x);
  return (short)((u + 0x7fffu + ((u >> 16) & 1u)) >> 16);
}
DEV s16x8 load8s(const short* p) { return *(const s16x8*)p; }

DEV void gld_lds16(const short* g, short* l) {
  __builtin_amdgcn_global_load_lds(
      (const __attribute__((address_space(1))) void*)g,
      (__attribute__((address_space(3))) void*)l, 16, 0, 0);
}

// ---------------------------------------------------------------- elementwise
__global__ __launch_bounds__(256) void split_pair(const float* __restrict__ X,
                                                  short* __restrict__ H,
                                                  short* __restrict__ L) {
  int i = (blockIdx.x * 256 + threadIdx.x) * 4;
  float4 x = *(const float4*)(X + i);
  float xs[4] = {x.x, x.y, x.z, x.w};
  s16x4 h4, l4;
#pragma unroll
  for (int e = 0; e < 4; ++e) {
    short h, l;
    split1(xs[e], h, l);
    h4[e] = h;
    l4[e] = l;
  }
  *(s16x4*)(H + i) = h4;
  *(s16x4*)(L + i) = l4;
}

__global__ __launch_bounds__(256) void cast_rne(const float* __restrict__ X,
                                                short* __restrict__ Y) {
  int i = (blockIdx.x * 256 + threadIdx.x) * 4;
  float4 x = *(const float4*)(X + i);
  float xs[4] = {x.x, x.y, x.z, x.w};
  s16x4 y4;
#pragma unroll
  for (int e = 0; e < 4; ++e) y4[e] = f2bf_rne(xs[e]);
  *(s16x4*)(Y + i) = y4;
}

// ---------------------------------------------------------------- merged Q+K projection
// Grid 1024: blocks 0-511 compute Q tiles (plain bf16 out, [B,H,S,DK]),
// blocks 512-1023 compute K tiles (hi/lo bf16 out, [B,H,S,DK]).
// Tile 128(M) x 64(N), BK=32, LDS double-buffered split K-loop.
__global__ __launch_bounds__(256) void gemm_qk(
    const short* __restrict__ qAh, const short* __restrict__ qAl,
    const short* __restrict__ Wqh, const short* __restrict__ Wql,
    const float* __restrict__ bq, short* __restrict__ Qo,
    const short* __restrict__ kAh, const short* __restrict__ kAl,
    const short* __restrict__ Wkh, const short* __restrict__ Wkl,
    const float* __restrict__ bk, short* __restrict__ Kho,
    short* __restrict__ Klo) {
  __shared__ short lds[2][12288];

  const int tid = threadIdx.x;
  const int lane = tid & 63, wv = tid >> 6;
  const int lo16 = lane & 15, quad = lane >> 4;
  const int sel = blockIdx.x >> 9;  // 0 = Q, 1 = K
  const int bid = blockIdx.x & 511;
  const int m0 = (bid & 31) * 128;
  const int n0 = (bid >> 5) * 64;

  const short* Agh = sel ? kAh : qAh;
  const short* Agl = sel ? kAl : qAl;
  const short* Wgh = sel ? Wkh : Wqh;
  const short* Wgl = sel ? Wkl : Wql;
  const float* bias = sel ? bk : bq;

  f32x4 acc[2][4];
#pragma unroll
  for (int mt = 0; mt < 2; ++mt)
#pragma unroll
    for (int nt = 0; nt < 4; ++nt) acc[mt][nt] = f32x4{0.f, 0.f, 0.f, 0.f};

  const int rw = tid >> 2, qw = tid & 3;
  const int ra0 = tid >> 2, ra1 = (tid + 256) >> 2;

  auto stage = [&](int k0, int buf) {
    short* sAh = lds[buf];
    short* sAl = lds[buf] + 4096;
    short* sWh = lds[buf] + 8192;
    short* sWl = lds[buf] + 10240;
    gld_lds16(Wgh + (size_t)(n0 + rw) * DD + k0 + qw * 8, sWh + tid * 8);
    gld_lds16(Wgl + (size_t)(n0 + rw) * DD + k0 + qw * 8, sWl + tid * 8);
    gld_lds16(Agh + (size_t)(m0 + ra0) * DD + k0 + qw * 8, sAh + tid * 8);
    gld_lds16(Agh + (size_t)(m0 + ra1) * DD + k0 + qw * 8, sAh + (tid + 256) * 8);
    gld_lds16(Agl + (size_t)(m0 + ra0) * DD + k0 + qw * 8, sAl + tid * 8);
    gld_lds16(Agl + (size_t)(m0 + ra1) * DD + k0 + qw * 8, sAl + (tid + 256) * 8);
  };

  stage(0, 0);

  for (int kk = 0; kk < DD / 32; ++kk) {
    __syncthreads();
    if (kk + 1 < DD / 32) stage((kk + 1) * 32, (kk + 1) & 1);

    const short* sAh = lds[kk & 1];
    const short* sAl = lds[kk & 1] + 4096;
    const short* sWh = lds[kk & 1] + 8192;
    const short* sWl = lds[kk & 1] + 10240;

    s16x8 ah[2], al[2], wh[4], wl[4];
#pragma unroll
    for (int mt = 0; mt < 2; ++mt) {
      const int r = wv * 32 + mt * 16 + lo16;
      ah[mt] = *(const s16x8*)&sAh[r * 32 + quad * 8];
      al[mt] = *(const s16x8*)&sAl[r * 32 + quad * 8];
    }
#pragma unroll
    for (int nt = 0; nt < 4; ++nt) {
      const int r = nt * 16 + lo16;
      wh[nt] = *(const s16x8*)&sWh[r * 32 + quad * 8];
      wl[nt] = *(const s16x8*)&sWl[r * 32 + quad * 8];
    }
#pragma unroll
    for (int mt = 0; mt < 2; ++mt)
#pragma unroll
      for (int nt = 0; nt < 4; ++nt) {
        acc[mt][nt] = mfma16(ah[mt], wh[nt], acc[mt][nt]);
        acc[mt][nt] = mfma16(ah[mt], wl[nt], acc[mt][nt]);
        acc[mt][nt] = mfma16(al[mt], wh[nt], acc[mt][nt]);
      }
  }

#pragma unroll
  for (int mt = 0; mt < 2; ++mt)
#pragma unroll
    for (int nt = 0; nt < 4; ++nt) {
      const int n = n0 + nt * 16 + lo16;
      const float bv = bias[n];
#pragma unroll
      for (int r = 0; r < 4; ++r) {
        const int m = m0 + wv * 32 + mt * 16 + quad * 4 + r;
        const float val = acc[mt][nt][r] + bv;
        const int b = m >> 11, s = m & 2047;
        const int h = n >> 6, dk = n & 63;
        size_t idx = ((size_t)(b * HH + h) * SS + s) * DKK + dk;
        if (sel == 0) {
          Qo[idx] = f2bf_rne(val);
        } else {
          short hh, ll;
          split1(val, hh, ll);
          Kho[idx] = hh;
          Klo[idx] = ll;
        }
      }
    }
}

// ---------------------------------------------------------------- GEMM C = A @ W^T + b
// EPI 1: plain A/W, out bf16 -> [B,H,DK,S] (V transposed)
// EPI 2: split A/W, out fp32 -> [4096,1024] (final output)
template <int SPLIT, int EPI>
__global__ __launch_bounds__(256) void gemm_tile(
    const short* __restrict__ Agh, const short* __restrict__ Agl,
    const short* __restrict__ Wgh, const short* __restrict__ Wgl,
    const float* __restrict__ bias, void* __restrict__ O1, void* __restrict__ O2) {
  __shared__ short lds[2][12288];

  const int tid = threadIdx.x;
  const int lane = tid & 63, wv = tid >> 6;
  const int lo16 = lane & 15, quad = lane >> 4;
  const int m0 = (blockIdx.x & 31) * 128;
  const int n0 = (blockIdx.x >> 5) * 64;

  f32x4 acc[2][4];
#pragma unroll
  for (int mt = 0; mt < 2; ++mt)
#pragma unroll
    for (int nt = 0; nt < 4; ++nt) acc[mt][nt] = f32x4{0.f, 0.f, 0.f, 0.f};

  const int rw = tid >> 2, qw = tid & 3;
  const int ra0 = tid >> 2, ra1 = (tid + 256) >> 2;

  auto stage = [&](int k0, int buf) {
    short* sAh = lds[buf];
    short* sAl = lds[buf] + 4096;
    short* sWh = lds[buf] + 8192;
    short* sWl = lds[buf] + 10240;
    gld_lds16(Wgh + (size_t)(n0 + rw) * DD + k0 + qw * 8, sWh + tid * 8);
    if constexpr (SPLIT)
      gld_lds16(Wgl + (size_t)(n0 + rw) * DD + k0 + qw * 8, sWl + tid * 8);
    gld_lds16(Agh + (size_t)(m0 + ra0) * DD + k0 + qw * 8, sAh + tid * 8);
    gld_lds16(Agh + (size_t)(m0 + ra1) * DD + k0 + qw * 8, sAh + (tid + 256) * 8);
    if constexpr (SPLIT) {
      gld_lds16(Agl + (size_t)(m0 + ra0) * DD + k0 + qw * 8, sAl + tid * 8);
      gld_lds16(Agl + (size_t)(m0 + ra1) * DD + k0 + qw * 8, sAl + (tid + 256) * 8);
    }
  };

  stage(0, 0);

  for (int kk = 0; kk < DD / 32; ++kk) {
    __syncthreads();
    if (kk + 1 < DD / 32) stage((kk + 1) * 32, (kk + 1) & 1);

    const short* sAh = lds[kk & 1];
    const short* sAl = lds[kk & 1] + 4096;
    const short* sWh = lds[kk & 1] + 8192;
    const short* sWl = lds[kk & 1] + 10240;

    s16x8 ah[2], al[2], wh[4], wl[4];
#pragma unroll
    for (int mt = 0; mt < 2; ++mt) {
      const int r = wv * 32 + mt * 16 + lo16;
      ah[mt] = *(const s16x8*)&sAh[r * 32 + quad * 8];
      if constexpr (SPLIT) al[mt] = *(const s16x8*)&sAl[r * 32 + quad * 8];
    }
#pragma unroll
    for (int nt = 0; nt < 4; ++nt) {
      const int r = nt * 16 + lo16;
      wh[nt] = *(const s16x8*)&sWh[r * 32 + quad * 8];
      if constexpr (SPLIT) wl[nt] = *(const s16x8*)&sWl[r * 32 + quad * 8];
    }
#pragma unroll
    for (int mt = 0; mt < 2; ++mt)
#pragma unroll
      for (int nt = 0; nt < 4; ++nt) {
        acc[mt][nt] = mfma16(ah[mt], wh[nt], acc[mt][nt]);
        if constexpr (SPLIT) {
          acc[mt][nt] = mfma16(ah[mt], wl[nt], acc[mt][nt]);
          acc[mt][nt] = mfma16(al[mt], wh[nt], acc[mt][nt]);
        }
      }
  }

#pragma unroll
  for (int mt = 0; mt < 2; ++mt)
#pragma unroll
    for (int nt = 0; nt < 4; ++nt) {
      const int n = n0 + nt * 16 + lo16;
      const float bv = bias[n];
#pragma unroll
      for (int r = 0; r < 4; ++r) {
        const int m = m0 + wv * 32 + mt * 16 + quad * 4 + r;
        const float val = acc[mt][nt][r] + bv;
        const int b = m >> 11, s = m & 2047;
        const int h = n >> 6, dk = n & 63;
        if constexpr (EPI == 1) {
          size_t idx = ((size_t)(b * HH + h) * DKK + dk) * SS + s;
          ((short*)O1)[idx] = f2bf_rne(val);
        } else {
          ((float*)O1)[(size_t)m * DD + n] = val;
        }
      }
    }
}

// ---------------------------------------------------------------- flash attention
// Block = 128 q-rows of one head (4 waves x 32 rows). K/V staged in LDS per
// 64-key iteration; next tile register-prefetched. No-max softmax. Q plain
// bf16; K hi/lo (2-term QK MFMA).
constexpr int PAD = 68;
constexpr int NKB = SS / 64;  // 32

__global__ __launch_bounds__(256, 2) void mha_attn(
    const short* __restrict__ Qh, const short* __restrict__ Kh,
    const short* __restrict__ Kl, const short* __restrict__ Vt,
    const int* __restrict__ mask, short* __restrict__ Ah,
    short* __restrict__ Al) {
  __shared__ short sKh[64 * PAD];
  __shared__ short sKl[64 * PAD];
  __shared__ short sV[64 * PAD];
  __shared__ short sP[4][32 * PAD];

  const int tid = threadIdx.x;
  const int lane = tid & 63, wv = tid >> 6;
  const int lo16 = lane & 15, quad = lane >> 4;
  const int bid = blockIdx.x;  // 512 blocks
  const int head = (bid & 7) * 4 + ((bid >> 3) & 3);  // = b*16 + h
  const int qblk = bid >> 5;                          // 0..15
  const int q0 = qblk * 128 + wv * 32;                // this wave's 32 q rows
  const int b = head >> 4;

  const size_t hbase = (size_t)head * SS;

  s16x8 qh[2][2];
#pragma unroll
  for (int rt = 0; rt < 2; ++rt) {
    size_t qb = (hbase + q0 + rt * 16 + lo16) * DKK + quad * 8;
#pragma unroll
    for (int c = 0; c < 2; ++c) qh[rt][c] = load8s(Qh + qb + c * 32);
  }

  f32x4 Oacc[2][4];
#pragma unroll
  for (int rt = 0; rt < 2; ++rt)
#pragma unroll
    for (int t = 0; t < 4; ++t) Oacc[rt][t] = f32x4{0.f, 0.f, 0.f, 0.f};
  float lsum[2][4];
#pragma unroll
  for (int rt = 0; rt < 2; ++rt)
#pragma unroll
    for (int r = 0; r < 4; ++r) lsum[rt][r] = 0.f;

  const int srow = tid >> 2;
  const int scol0 = (tid & 3) * 8;

  s16x8 rKh[2], rKl[2], rV[2];
#pragma unroll
  for (int i = 0; i < 2; ++i) {
    const int sc_ = scol0 + i * 32;
    rKh[i] = load8s(Kh + (hbase + srow) * DKK + sc_);
    rKl[i] = load8s(Kl + (hbase + srow) * DKK + sc_);
    rV[i] = load8s(Vt + ((size_t)head * DKK + srow) * SS + sc_);
  }

  for (int kb = 0; kb < NKB; ++kb) {
    const int k0g = kb * 64;
#pragma unroll
    for (int i = 0; i < 2; ++i) {
      const int sc_ = scol0 + i * 32;
      *(s16x8*)&sKh[srow * PAD + sc_] = rKh[i];
      *(s16x8*)&sKl[srow * PAD + sc_] = rKl[i];
      *(s16x8*)&sV[srow * PAD + sc_] = rV[i];
    }
    __syncthreads();

    if (kb + 1 < NKB) {
      const int k0n = k0g + 64;
#pragma unroll
      for (int i = 0; i < 2; ++i) {
        const int sc_ = scol0 + i * 32;
        rKh[i] = load8s(Kh + (hbase + k0n + srow) * DKK + sc_);
        rKl[i] = load8s(Kl + (hbase + k0n + srow) * DKK + sc_);
        rV[i] = load8s(Vt + ((size_t)head * DKK + srow) * SS + k0n + sc_);
      }
    }

    f32x4 sc4[2][4];
    int mv[4];
#pragma unroll
    for (int sub = 0; sub < 4; ++sub) {
      mv[sub] = mask[b * SS + k0g + sub * 16 + lo16];
      sc4[0][sub] = f32x4{0.f, 0.f, 0.f, 0.f};
      sc4[1][sub] = f32x4{0.f, 0.f, 0.f, 0.f};
      const int krow = sub * 16 + lo16;
#pragma unroll
      for (int c = 0; c < 2; ++c) {
        s16x8 kh = *(const s16x8*)&sKh[krow * PAD + c * 32 + quad * 8];
        s16x8 kl = *(const s16x8*)&sKl[krow * PAD + c * 32 + quad * 8];
#pragma unroll
        for (int rt = 0; rt < 2; ++rt) {
          sc4[rt][sub] = mfma16(qh[rt][c], kh, sc4[rt][sub]);
          sc4[rt][sub] = mfma16(qh[rt][c], kl, sc4[rt][sub]);
        }
      }
    }

#pragma unroll
    for (int rt = 0; rt < 2; ++rt)
#pragma unroll
      for (int sub = 0; sub < 4; ++sub)
#pragma unroll
        for (int r = 0; r < 4; ++r) {
          float p = __expf(sc4[rt][sub][r] * 0.125f);
          p = mv[sub] ? p : 0.f;
          lsum[rt][r] += p;
          sP[wv][(rt * 16 + quad * 4 + r) * PAD + sub * 16 + lo16] = f2bf_rne(p);
        }

    s16x8 pa[2][2];
#pragma unroll
    for (int rt = 0; rt < 2; ++rt)
#pragma unroll
      for (int c = 0; c < 2; ++c)
        pa[rt][c] = *(const s16x8*)&sP[wv][(rt * 16 + lo16) * PAD + c * 32 + quad * 8];
#pragma unroll
    for (int t = 0; t < 4; ++t)
#pragma unroll
      for (int c = 0; c < 2; ++c) {
        s16x8 vb = *(const s16x8*)&sV[(t * 16 + lo16) * PAD + c * 32 + quad * 8];
#pragma unroll
        for (int rt = 0; rt < 2; ++rt)
          Oacc[rt][t] = mfma16(pa[rt][c], vb, Oacc[rt][t]);
      }
    __syncthreads();
  }

  const int h = head & 15;
#pragma unroll
  for (int rt = 0; rt < 2; ++rt)
#pragma unroll
    for (int r = 0; r < 4; ++r) {
      float s = lsum[rt][r];
#pragma unroll
      for (int off = 1; off < 16; off <<= 1) s += __shfl_xor(s, off);
      const float rinv = 1.0f / s;
#pragma unroll
      for (int t = 0; t < 4; ++t) {
        const float val = Oacc[rt][t][r] * rinv;
        const int row = q0 + rt * 16 + quad * 4 + r;
        const int col = h * DKK + t * 16 + lo16;
        const size_t idx = ((size_t)b * SS + row) * DD + col;
        short hh, ll;
        split1(val, hh, ll);
        Ah[idx] = hh;
        Al[idx] = ll;
      }
    }
}

// ---------------------------------------------------------------- launch
extern "C" void kernel_launch(void* const* d_in, const int* in_sizes, int n_in,
                              void* d_out, int out_size, void* d_ws, size_t ws_size,
                              hipStream_t stream) {
  const float* q = (const float*)d_in[0];
  const float* k = (const float*)d_in[1];
  const float* v = (const float*)d_in[2];
  const int* mask = (const int*)d_in[3];
  const float* Wq = (const float*)d_in[4];
  const float* bq = (const float*)d_in[5];
  const float* Wk = (const float*)d_in[6];
  const float* bk = (const float*)d_in[7];
  const float* Wv = (const float*)d_in[8];
  const float* bv = (const float*)d_in[9];
  const float* Wo = (const float*)d_in[10];
  const float* bo = (const float*)d_in[11];

  char* ws = (char*)d_ws;
  size_t off = 0;
  auto take = [&](size_t bytes) {
    char* p = ws + off;
    off += (bytes + 255) & ~(size_t)255;
    return p;
  };
  const size_t WE = (size_t)DD * DD;       // 1,048,576
  const size_t TE = (size_t)BB * SS * DD;  // 4,194,304

  short* Wqh = (short*)take(WE * 2);
  short* Wql = (short*)take(WE * 2);
  short* Wkh = (short*)take(WE * 2);
  short* Wkl = (short*)take(WE * 2);
  short* Wvh = (short*)take(WE * 2);
  short* Woh = (short*)take(WE * 2);
  short* Wol = (short*)take(WE * 2);
  short* qH = (short*)take(TE * 2);
  short* qL = (short*)take(TE * 2);
  short* kH = (short*)take(TE * 2);
  short* kL = (short*)take(TE * 2);
  short* Qh = (short*)take(TE * 2);
  short* Kh = (short*)take(TE * 2);
  short* Kl = (short*)take(TE * 2);
  (void)ws_size;  // 70 MB peak (aliased below)
  // aliases (lifetimes disjoint on the serial stream):
  short* vH = qH;  // v cast, after gemm_qk consumed qH
  short* Vt = qL;  // V-proj out, after gemm_qk consumed qL
  short* aH = kH;  // attn out hi, after gemm_qk consumed kH
  short* aL = kL;  // attn out lo

  // weights
  split_pair<<<1024, 256, 0, stream>>>(Wq, Wqh, Wql);
  split_pair<<<1024, 256, 0, stream>>>(Wk, Wkh, Wkl);
  split_pair<<<1024, 256, 0, stream>>>(Wo, Woh, Wol);
  cast_rne<<<1024, 256, 0, stream>>>(Wv, Wvh);

  // activation splits
  split_pair<<<4096, 256, 0, stream>>>(q, qH, qL);
  split_pair<<<4096, 256, 0, stream>>>(k, kH, kL);

  // merged Q+K projection (1024 blocks -> 3 blocks/CU)
  gemm_qk<<<1024, 256, 0, stream>>>(qH, qL, Wqh, Wql, bq, Qh,
                                    kH, kL, Wkh, Wkl, bk, Kh, Kl);

  // V projection (plain bf16, transposed output)
  cast_rne<<<4096, 256, 0, stream>>>(v, vH);
  gemm_tile<0, 1><<<512, 256, 0, stream>>>(vH, nullptr, Wvh, nullptr, bv, Vt, nullptr);

  // attention
  mha_attn<<<512, 256, 0, stream>>>(Qh, Kh, Kl, Vt, mask, aH, aL);

  // output projection
  gemm_tile<1, 2><<<512, 256, 0, stream>>>(aH, aL, Woh, Wol, bo, d_out, nullptr);
}